// Round 1
// baseline (393.246 us; speedup 1.0000x reference)
//
#include <hip/hip_runtime.h>
#include <math.h>

// Problem constants (from reference): D_MODEL=4, D_INNER=8, D_STATE=16, D_CONV=4, DT_RANK=1
// x: (B=4, N=6, H=128, W=128) f32. L = 98304.
#define HWSZ  16384
#define LTOT  98304
#define NB    4
#define TCH   192          // chunk length
#define NCH   512          // LTOT / TCH
#define PADT  193          // d-major LDS stride (conflict-free: 193 % 32 == 1)

__device__ __forceinline__ float siluf(float x){ return x / (1.f + expf(-x)); }
__device__ __forceinline__ float softplusf(float x){ return fmaxf(x, 0.f) + log1pf(expf(-fabsf(x))); }

// perm k=0 (scanA): i = n*HW + r -> spatial n*HW + sp[r]
__device__ __forceinline__ int rho0(int i, const int* __restrict__ sp){
  int n = i >> 14; int r = i & (HWSZ - 1);
  return (n << 14) + sp[r];
}
// perm k=1 (scanB): i = r*6 + n ; tid = (r even ? n : 5-n) -> tid*HW + sp[r]
__device__ __forceinline__ int rho1(int i, const int* __restrict__ sp){
  unsigned ui = (unsigned)i;
  unsigned r = ui / 6u; unsigned n = ui - r * 6u;
  unsigned t = (r & 1u) ? (5u - n) : n;
  return (int)((t << 14) + (unsigned)sp[r]);
}
// k=2 is rho0(L-1-i), k=3 is rho1(L-1-i)

// ---------------- perm build: stable argsort of d2 over 128x128 ----------------
__global__ __launch_bounds__(256) void k_hist(int* __restrict__ prefix){
  __shared__ int hist[8193];
  __shared__ int part[256];
  const int tid = threadIdx.x;
  for (int v = tid; v < 8193; v += 256) hist[v] = 0;
  __syncthreads();
  for (int j = tid; j < HWSZ; j += 256){
    int dy = (j >> 7) - 64, dx = (j & 127) - 64;
    atomicAdd(&hist[dy*dy + dx*dx], 1);
  }
  __syncthreads();
  const int base = tid * 33;
  int sum = 0;
  for (int m = 0; m < 33; ++m){ int v = base + m; if (v < 8193) sum += hist[v]; }
  part[tid] = sum;
  __syncthreads();
  if (tid == 0){
    int run = 0;
    for (int t = 0; t < 256; ++t){ int c = part[t]; part[t] = run; run += c; }
  }
  __syncthreads();
  int run = part[tid];
  for (int m = 0; m < 33; ++m){
    int v = base + m;
    if (v < 8193){ int c = hist[v]; prefix[v] = run; run += c; }
  }
}

__global__ __launch_bounds__(256) void k_rank(const int* __restrict__ prefix, int* __restrict__ sp){
  const int j = blockIdx.x * 256 + threadIdx.x;   // 0..16383
  const int y = j >> 7, x = j & 127;
  const int dy = y - 64, dx = x - 64;
  const int v = dy*dy + dx*dx;
  int cnt = prefix[v];                            // elements with smaller d2
  // same-bin elements with smaller flat index: all rows y' < y, plus same-row mirror
  for (int yp = 0; yp < y; ++yp){
    int dyp = yp - 64;
    int tt = v - dyp*dyp;
    if (tt < 0) continue;
    int rr = (int)sqrtf((float)tt);
    while (rr * rr > tt) --rr;
    while ((rr + 1) * (rr + 1) <= tt) ++rr;
    if (rr * rr == tt){
      cnt += (rr <= 64) ? 1 : 0;                  // x = 64 - rr in range
      cnt += (rr >= 1 && rr <= 63) ? 1 : 0;       // x = 64 + rr in range, distinct
    }
  }
  if (x > 64) cnt += 1;                           // mirror 128-x precedes
  sp[cnt] = j;
}

// ---------------- chunk kernels ----------------
template<bool FINAL>
__global__ __launch_bounds__(192)
void k_chunk(const float* __restrict__ X,
             const float* __restrict__ dww, const float* __restrict__ dwb,
             const float* __restrict__ ipw,
             const float* __restrict__ c1w, const float* __restrict__ c1b,
             const float* __restrict__ xpw,
             const float* __restrict__ dtpw, const float* __restrict__ dtpb,
             const float* __restrict__ Alog, const float* __restrict__ Dp,
             const float* __restrict__ opw,
             const float* __restrict__ lng, const float* __restrict__ lnb,
             const int* __restrict__ sp, const float* __restrict__ hin,
             float* __restrict__ chA, float* __restrict__ chB,
             float* __restrict__ outbuf)
{
  const int c = blockIdx.x, b = blockIdx.y;
  const int c0 = c * TCH;
  const int tid = threadIdx.x;
  const float* Xb = X + (size_t)b * LTOT;

  __shared__ float s_pre[(TCH + 3) * 9];            // xm_pre halo buffer, stride 9 (conflict-free)
  __shared__ float s_dt[8 * PADT];
  __shared__ float s_xm[8 * PADT];
  __shared__ float s_Bv[16 * PADT];
  __shared__ float s_Cv[FINAL ? 16 * PADT : 1];
  __shared__ float s_zs[FINAL ? 8 * PADT : 1];
  float* s_y = s_pre;                               // reuse after step B (dead)

  // ---- step A: u -> xm_pre (and silu(z) if FINAL) for positions [c0-3, c0+TCH)
  for (int m = tid; m < TCH + 3; m += 192){
    const int i = c0 - 3 + m;
    if (i < 0){
      #pragma unroll
      for (int d = 0; d < 8; ++d) s_pre[m*9 + d] = 0.f;
      continue;
    }
    const int i2 = LTOT - 1 - i;
    const bool okm = (i > 0), okp = (i < LTOT - 1);
    int q[12];
    q[0]  = okm ? rho0(i - 1, sp) : 0;
    q[1]  =       rho0(i,     sp);
    q[2]  = okp ? rho0(i + 1, sp) : 0;
    q[3]  = okm ? rho1(i - 1, sp) : 0;
    q[4]  =       rho1(i,     sp);
    q[5]  = okp ? rho1(i + 1, sp) : 0;
    q[6]  = okm ? rho0(i2 + 1, sp) : 0;   // scan2[j] = X[rho0(L-1-j)]
    q[7]  =       rho0(i2,     sp);
    q[8]  = okp ? rho0(i2 - 1, sp) : 0;
    q[9]  = okm ? rho1(i2 + 1, sp) : 0;
    q[10] =       rho1(i2,     sp);
    q[11] = okp ? rho1(i2 - 1, sp) : 0;
    float xv[12];
    #pragma unroll
    for (int t = 0; t < 12; ++t) xv[t] = Xb[q[t]];
    if (!okm){ xv[0] = 0.f; xv[3] = 0.f; xv[6] = 0.f; xv[9]  = 0.f; }
    if (!okp){ xv[2] = 0.f; xv[5] = 0.f; xv[8] = 0.f; xv[11] = 0.f; }
    float u[4];
    #pragma unroll
    for (int k = 0; k < 4; ++k){
      float acc = dwb[k];
      acc = fmaf(dww[k*3+0], xv[k*3+0], acc);
      acc = fmaf(dww[k*3+1], xv[k*3+1], acc);
      acc = fmaf(dww[k*3+2], xv[k*3+2], acc);
      u[k] = siluf(acc);
    }
    #pragma unroll
    for (int d = 0; d < 8; ++d){
      float acc =      ipw[d*4+0] * u[0];
      acc = fmaf(ipw[d*4+1], u[1], acc);
      acc = fmaf(ipw[d*4+2], u[2], acc);
      acc = fmaf(ipw[d*4+3], u[3], acc);
      s_pre[m*9 + d] = acc;
    }
    if (FINAL && m >= 3){
      const int t0 = m - 3;
      #pragma unroll
      for (int d = 0; d < 8; ++d){
        float acc =      ipw[(8+d)*4+0] * u[0];
        acc = fmaf(ipw[(8+d)*4+1], u[1], acc);
        acc = fmaf(ipw[(8+d)*4+2], u[2], acc);
        acc = fmaf(ipw[(8+d)*4+3], u[3], acc);
        s_zs[d*PADT + t0] = siluf(acc);
      }
    }
  }
  __syncthreads();

  // ---- step B: causal conv4 + silu -> xm ; x_proj -> dt_raw, B (, C) ; softplus dt
  {
    const int t = tid;   // 0..191 == TCH-1
    float xm[8];
    #pragma unroll
    for (int d = 0; d < 8; ++d){
      float acc = c1b[d];
      #pragma unroll
      for (int tau = 0; tau < 4; ++tau)
        acc = fmaf(c1w[d*4+tau], s_pre[(t+tau)*9 + d], acc);
      float v = siluf(acc);
      xm[d] = v;
      s_xm[d*PADT + t] = v;
    }
    float dtr = xpw[0] * xm[0];
    #pragma unroll
    for (int d = 1; d < 8; ++d) dtr = fmaf(xpw[d], xm[d], dtr);
    #pragma unroll
    for (int s = 0; s < 16; ++s){
      float acc = xpw[(1+s)*8] * xm[0];
      #pragma unroll
      for (int d = 1; d < 8; ++d) acc = fmaf(xpw[(1+s)*8+d], xm[d], acc);
      s_Bv[s*PADT + t] = acc;
      if constexpr (FINAL){
        float acc2 = xpw[(17+s)*8] * xm[0];
        #pragma unroll
        for (int d = 1; d < 8; ++d) acc2 = fmaf(xpw[(17+s)*8+d], xm[d], acc2);
        s_Cv[s*PADT + t] = acc2;
      }
    }
    #pragma unroll
    for (int d = 0; d < 8; ++d)
      s_dt[d*PADT + t] = softplusf(fmaf(dtpw[d], dtr, dtpb[d]));
  }
  __syncthreads();

  // ---- step C: per-(d,s) scan over the chunk
  if (tid < 128){
    const int d = tid >> 4, s = tid & 15;
    const float Ads = -expf(Alog[(d << 4) + s]);
    float h  = 0.f;
    float ap = 1.f;
    if constexpr (FINAL) h = hin[((size_t)b * NCH + c) * 128 + tid];
    for (int t = 0; t < TCH; ++t){
      float dtv = s_dt[d*PADT + t];
      float dA  = expf(dtv * Ads);
      float bx  = dtv * s_Bv[s*PADT + t] * s_xm[d*PADT + t];
      h = fmaf(dA, h, bx);
      if constexpr (FINAL){
        float hc = h * s_Cv[s*PADT + t];
        hc += __shfl_xor(hc, 8, 16);
        hc += __shfl_xor(hc, 4, 16);
        hc += __shfl_xor(hc, 2, 16);
        hc += __shfl_xor(hc, 1, 16);
        if (s == 0) s_y[d*PADT + t] = hc;
      } else {
        ap *= dA;
      }
    }
    if constexpr (!FINAL){
      const size_t base = ((size_t)b * NCH + c) * 128 + tid;
      chA[base] = ap;
      chB[base] = h;
    }
  }

  // ---- step D (FINAL): skip + gate + out_proj + LN -> outbuf[b, i, 0:4]
  if constexpr (FINAL){
    __syncthreads();
    const int t = tid;
    const int i = c0 + t;
    float y[8];
    #pragma unroll
    for (int d = 0; d < 8; ++d)
      y[d] = (s_y[d*PADT + t] + s_xm[d*PADT + t] * Dp[d]) * s_zs[d*PADT + t];
    float o[4];
    #pragma unroll
    for (int e = 0; e < 4; ++e){
      float acc = opw[e*8] * y[0];
      #pragma unroll
      for (int d = 1; d < 8; ++d) acc = fmaf(opw[e*8+d], y[d], acc);
      o[e] = acc;
    }
    const float mu = 0.25f * (o[0] + o[1] + o[2] + o[3]);
    const float v0 = o[0] - mu, v1 = o[1] - mu, v2 = o[2] - mu, v3 = o[3] - mu;
    const float inv = rsqrtf(0.25f * (v0*v0 + v1*v1 + v2*v2 + v3*v3) + 1e-5f);
    float4 r;
    r.x = fmaf(v0 * inv, lng[0], lnb[0]);
    r.y = fmaf(v1 * inv, lng[1], lnb[1]);
    r.z = fmaf(v2 * inv, lng[2], lnb[2]);
    r.w = fmaf(v3 * inv, lng[3], lnb[3]);
    *reinterpret_cast<float4*>(outbuf + ((size_t)b * LTOT + i) * 4) = r;
  }
}

// ---------------- chunk-prefix combine ----------------
__global__ __launch_bounds__(512) void k_combine(const float* __restrict__ chA,
                                                 const float* __restrict__ chB,
                                                 float* __restrict__ hin){
  const int tb  = threadIdx.x;           // 0..511
  const int b   = tb >> 7;
  const int idx = tb & 127;
  const float* pa = chA + (size_t)b * NCH * 128 + idx;
  const float* pb = chB + (size_t)b * NCH * 128 + idx;
  float*       ph = hin + (size_t)b * NCH * 128 + idx;
  float h = 0.f;
  float a[16], v[16];
  #pragma unroll
  for (int m = 0; m < 16; ++m){ a[m] = pa[m*128]; v[m] = pb[m*128]; }
  for (int c0 = 0; c0 < NCH; c0 += 16){
    float a2[16], v2[16];
    if (c0 + 16 < NCH){
      #pragma unroll
      for (int m = 0; m < 16; ++m){ a2[m] = pa[(c0+16+m)*128]; v2[m] = pb[(c0+16+m)*128]; }
    } else {
      #pragma unroll
      for (int m = 0; m < 16; ++m){ a2[m] = 0.f; v2[m] = 0.f; }
    }
    #pragma unroll
    for (int m = 0; m < 16; ++m){ ph[(c0+m)*128] = h; h = fmaf(a[m], h, v[m]); }
    #pragma unroll
    for (int m = 0; m < 16; ++m){ a[m] = a2[m]; v[m] = v2[m]; }
  }
}

// ---------------- final gather + mean ----------------
__global__ __launch_bounds__(256) void k_final(const float* __restrict__ outbuf,
                                               const int* __restrict__ sp,
                                               float* __restrict__ out){
  const int l = blockIdx.x * 256 + threadIdx.x;   // spatial flat index 0..L-1
  const int b = blockIdx.y;
  const int q0 = rho0(l, sp), q1 = rho1(l, sp);
  const int j  = LTOT - 1 - l;
  const int q2 = rho0(j, sp), q3 = rho1(j, sp);
  const float* ob = outbuf + (size_t)b * LTOT * 4;
  out[(size_t)b * LTOT + l] =
      0.25f * (ob[q0*4 + 0] + ob[q1*4 + 1] + ob[q2*4 + 2] + ob[q3*4 + 3]);
}

extern "C" void kernel_launch(void* const* d_in, const int* in_sizes, int n_in,
                              void* d_out, int out_size, void* d_ws, size_t ws_size,
                              hipStream_t stream) {
  const float* X    = (const float*)d_in[0];   // (4,6,128,128)
  const float* dww  = (const float*)d_in[1];   // (4,1,3)
  const float* dwb  = (const float*)d_in[2];   // (4)
  const float* ipw  = (const float*)d_in[3];   // (16,4)
  const float* c1w  = (const float*)d_in[4];   // (8,1,4)
  const float* c1b  = (const float*)d_in[5];   // (8)
  const float* xpw  = (const float*)d_in[6];   // (33,8)
  const float* dtpw = (const float*)d_in[7];   // (8,1)
  const float* dtpb = (const float*)d_in[8];   // (8)
  const float* Alog = (const float*)d_in[9];   // (8,16)
  const float* Dp   = (const float*)d_in[10];  // (8)
  const float* opw  = (const float*)d_in[11];  // (4,8)
  const float* lng  = (const float*)d_in[12];  // (4)
  const float* lnb  = (const float*)d_in[13];  // (4)
  float* out = (float*)d_out;

  // workspace layout (all fully written before read each call):
  //   [0)           sp      16384 int
  //   [16384)       prefix   8193 int
  //   [24580)       hin     NB*NCH*128 f32          (1 MB)
  //   [24580+hin)   outbuf  NB*LTOT*4  f32          (6.3 MB); chA/chB alias its head:
  //                 chA = outbuf[0 .. NB*NCH*128), chB next — dead before outbuf is written.
  int* wsI    = (int*)d_ws;
  int* sp     = wsI;
  int* prefix = wsI + 16384;
  float* hin    = (float*)(wsI + 24580);
  float* outbuf = hin + (size_t)NB * NCH * 128;
  float* chA    = outbuf;
  float* chB    = outbuf + (size_t)NB * NCH * 128;

  k_hist<<<1, 256, 0, stream>>>(prefix);
  k_rank<<<64, 256, 0, stream>>>(prefix, sp);
  k_chunk<false><<<dim3(NCH, NB), 192, 0, stream>>>(X, dww, dwb, ipw, c1w, c1b, xpw,
      dtpw, dtpb, Alog, Dp, opw, lng, lnb, sp, (const float*)nullptr, chA, chB, (float*)nullptr);
  k_combine<<<1, 512, 0, stream>>>(chA, chB, hin);
  k_chunk<true><<<dim3(NCH, NB), 192, 0, stream>>>(X, dww, dwb, ipw, c1w, c1b, xpw,
      dtpw, dtpb, Alog, Dp, opw, lng, lnb, sp, hin, (float*)nullptr, (float*)nullptr, outbuf);
  k_final<<<dim3(LTOT / 256, NB), 256, 0, stream>>>(outbuf, sp, out);
}

// Round 2
// 281.097 us; speedup vs baseline: 1.3990x; 1.3990x over previous
//
#include <hip/hip_runtime.h>
#include <math.h>

// Problem constants (from reference): D_MODEL=4, D_INNER=8, D_STATE=16, D_CONV=4, DT_RANK=1
// x: (B=4, N=6, H=128, W=128) f32. L = 98304.
#define HWSZ  16384
#define LTOT  98304
#define NB    4
#define TCH   192          // chunk length
#define NCH   512          // LTOT / TCH
#define PADT  193          // s-major LDS stride for B/C/zs (193 % 32 == 1: conflict-free scalar)
#define SD    196          // d-major stride for dt/xm (16B-aligned float4 broadcast, disjoint bank quads)
#define SY    196          // y stride (float4 stores, disjoint bank quads per d)

__device__ __forceinline__ float siluf(float x){ return x / (1.f + expf(-x)); }
__device__ __forceinline__ float softplusf(float x){ return fmaxf(x, 0.f) + log1pf(expf(-fabsf(x))); }

// 16-lane (row-aligned) sum via DPP butterflies — pure VALU, no DS ops.
__device__ __forceinline__ float red16(float x){
  int v;
  v = __float_as_int(x);
  x += __int_as_float(__builtin_amdgcn_update_dpp(0, v, 0xB1, 0xF, 0xF, true));   // quad_perm xor1
  v = __float_as_int(x);
  x += __int_as_float(__builtin_amdgcn_update_dpp(0, v, 0x4E, 0xF, 0xF, true));   // quad_perm xor2
  v = __float_as_int(x);
  x += __int_as_float(__builtin_amdgcn_update_dpp(0, v, 0x141, 0xF, 0xF, true));  // row_half_mirror
  v = __float_as_int(x);
  x += __int_as_float(__builtin_amdgcn_update_dpp(0, v, 0x140, 0xF, 0xF, true));  // row_mirror
  return x;
}

// perm k=0 (scanA): i = n*HW + r -> spatial n*HW + sp[r]
__device__ __forceinline__ int rho0(int i, const int* __restrict__ sp){
  int n = i >> 14; int r = i & (HWSZ - 1);
  return (n << 14) + sp[r];
}
// perm k=1 (scanB): i = r*6 + n ; tid = (r even ? n : 5-n) -> tid*HW + sp[r]
__device__ __forceinline__ int rho1(int i, const int* __restrict__ sp){
  unsigned ui = (unsigned)i;
  unsigned r = ui / 6u; unsigned n = ui - r * 6u;
  unsigned t = (r & 1u) ? (5u - n) : n;
  return (int)((t << 14) + (unsigned)sp[r]);
}
// k=2 is rho0(L-1-i), k=3 is rho1(L-1-i)

// ---------------- perm build: stable argsort of d2 over 128x128 ----------------
__global__ __launch_bounds__(256) void k_hist(int* __restrict__ prefix){
  __shared__ int hist[8193];
  __shared__ int part[256];
  const int tid = threadIdx.x;
  for (int v = tid; v < 8193; v += 256) hist[v] = 0;
  __syncthreads();
  for (int j = tid; j < HWSZ; j += 256){
    int dy = (j >> 7) - 64, dx = (j & 127) - 64;
    atomicAdd(&hist[dy*dy + dx*dx], 1);
  }
  __syncthreads();
  const int base = tid * 33;
  int sum = 0;
  for (int m = 0; m < 33; ++m){ int v = base + m; if (v < 8193) sum += hist[v]; }
  part[tid] = sum;
  __syncthreads();
  if (tid == 0){
    int run = 0;
    for (int t = 0; t < 256; ++t){ int c = part[t]; part[t] = run; run += c; }
  }
  __syncthreads();
  int run = part[tid];
  for (int m = 0; m < 33; ++m){
    int v = base + m;
    if (v < 8193){ int c = hist[v]; prefix[v] = run; run += c; }
  }
}

__global__ __launch_bounds__(256) void k_rank(const int* __restrict__ prefix, int* __restrict__ sp){
  const int j = blockIdx.x * 256 + threadIdx.x;   // 0..16383
  const int y = j >> 7, x = j & 127;
  const int dy = y - 64, dx = x - 64;
  const int v = dy*dy + dx*dx;
  int cnt = prefix[v];                            // elements with smaller d2
  // same-bin elements with smaller flat index: all rows y' < y, plus same-row mirror
  for (int yp = 0; yp < y; ++yp){
    int dyp = yp - 64;
    int tt = v - dyp*dyp;
    if (tt < 0) continue;
    int rr = (int)sqrtf((float)tt);
    while (rr * rr > tt) --rr;
    while ((rr + 1) * (rr + 1) <= tt) ++rr;
    if (rr * rr == tt){
      cnt += (rr <= 64) ? 1 : 0;                  // x = 64 - rr in range
      cnt += (rr >= 1 && rr <= 63) ? 1 : 0;       // x = 64 + rr in range, distinct
    }
  }
  if (x > 64) cnt += 1;                           // mirror 128-x precedes
  sp[cnt] = j;
}

// ---------------- chunk kernels ----------------
template<bool FINAL>
__global__ __launch_bounds__(192)
void k_chunk(const float* __restrict__ X,
             const float* __restrict__ dww, const float* __restrict__ dwb,
             const float* __restrict__ ipw,
             const float* __restrict__ c1w, const float* __restrict__ c1b,
             const float* __restrict__ xpw,
             const float* __restrict__ dtpw, const float* __restrict__ dtpb,
             const float* __restrict__ Alog, const float* __restrict__ Dp,
             const float* __restrict__ opw,
             const float* __restrict__ lng, const float* __restrict__ lnb,
             const int* __restrict__ sp, const float* __restrict__ hin,
             float* __restrict__ chA, float* __restrict__ chB,
             float* __restrict__ outbuf)
{
  const int c = blockIdx.x, b = blockIdx.y;
  const int c0 = c * TCH;
  const int tid = threadIdx.x;
  const float* Xb = X + (size_t)b * LTOT;

  __shared__ __align__(16) float s_pre[(TCH + 3) * 9];   // xm_pre halo, stride 9; reused as s_y
  __shared__ __align__(16) float s_dt[8 * SD];
  __shared__ __align__(16) float s_xm[8 * SD];
  __shared__ float s_Bv[16 * PADT];
  __shared__ float s_Cv[FINAL ? 16 * PADT : 1];
  __shared__ float s_zs[FINAL ? 8 * PADT : 1];
  float* s_y = s_pre;                               // reuse after step B (dead); stride SY

  // ---- step A: u -> xm_pre (and silu(z) if FINAL) for positions [c0-3, c0+TCH)
  for (int m = tid; m < TCH + 3; m += 192){
    const int i = c0 - 3 + m;
    if (i < 0){
      #pragma unroll
      for (int d = 0; d < 8; ++d) s_pre[m*9 + d] = 0.f;
      continue;
    }
    const int i2 = LTOT - 1 - i;
    const bool okm = (i > 0), okp = (i < LTOT - 1);
    int q[12];
    q[0]  = okm ? rho0(i - 1, sp) : 0;
    q[1]  =       rho0(i,     sp);
    q[2]  = okp ? rho0(i + 1, sp) : 0;
    q[3]  = okm ? rho1(i - 1, sp) : 0;
    q[4]  =       rho1(i,     sp);
    q[5]  = okp ? rho1(i + 1, sp) : 0;
    q[6]  = okm ? rho0(i2 + 1, sp) : 0;   // scan2[j] = X[rho0(L-1-j)]
    q[7]  =       rho0(i2,     sp);
    q[8]  = okp ? rho0(i2 - 1, sp) : 0;
    q[9]  = okm ? rho1(i2 + 1, sp) : 0;
    q[10] =       rho1(i2,     sp);
    q[11] = okp ? rho1(i2 - 1, sp) : 0;
    float xv[12];
    #pragma unroll
    for (int t = 0; t < 12; ++t) xv[t] = Xb[q[t]];
    if (!okm){ xv[0] = 0.f; xv[3] = 0.f; xv[6] = 0.f; xv[9]  = 0.f; }
    if (!okp){ xv[2] = 0.f; xv[5] = 0.f; xv[8] = 0.f; xv[11] = 0.f; }
    float u[4];
    #pragma unroll
    for (int k = 0; k < 4; ++k){
      float acc = dwb[k];
      acc = fmaf(dww[k*3+0], xv[k*3+0], acc);
      acc = fmaf(dww[k*3+1], xv[k*3+1], acc);
      acc = fmaf(dww[k*3+2], xv[k*3+2], acc);
      u[k] = siluf(acc);
    }
    #pragma unroll
    for (int d = 0; d < 8; ++d){
      float acc =      ipw[d*4+0] * u[0];
      acc = fmaf(ipw[d*4+1], u[1], acc);
      acc = fmaf(ipw[d*4+2], u[2], acc);
      acc = fmaf(ipw[d*4+3], u[3], acc);
      s_pre[m*9 + d] = acc;
    }
    if (FINAL && m >= 3){
      const int t0 = m - 3;
      #pragma unroll
      for (int d = 0; d < 8; ++d){
        float acc =      ipw[(8+d)*4+0] * u[0];
        acc = fmaf(ipw[(8+d)*4+1], u[1], acc);
        acc = fmaf(ipw[(8+d)*4+2], u[2], acc);
        acc = fmaf(ipw[(8+d)*4+3], u[3], acc);
        s_zs[d*PADT + t0] = siluf(acc);
      }
    }
  }
  __syncthreads();

  // ---- step B: causal conv4 + silu -> xm ; x_proj -> dt_raw, B (, C) ; softplus dt
  {
    const int t = tid;   // 0..191 == TCH-1
    float xm[8];
    #pragma unroll
    for (int d = 0; d < 8; ++d){
      float acc = c1b[d];
      #pragma unroll
      for (int tau = 0; tau < 4; ++tau)
        acc = fmaf(c1w[d*4+tau], s_pre[(t+tau)*9 + d], acc);
      float v = siluf(acc);
      xm[d] = v;
      s_xm[d*SD + t] = v;
    }
    float dtr = xpw[0] * xm[0];
    #pragma unroll
    for (int d = 1; d < 8; ++d) dtr = fmaf(xpw[d], xm[d], dtr);
    #pragma unroll
    for (int s = 0; s < 16; ++s){
      float acc = xpw[(1+s)*8] * xm[0];
      #pragma unroll
      for (int d = 1; d < 8; ++d) acc = fmaf(xpw[(1+s)*8+d], xm[d], acc);
      s_Bv[s*PADT + t] = acc;
      if constexpr (FINAL){
        float acc2 = xpw[(17+s)*8] * xm[0];
        #pragma unroll
        for (int d = 1; d < 8; ++d) acc2 = fmaf(xpw[(17+s)*8+d], xm[d], acc2);
        s_Cv[s*PADT + t] = acc2;
      }
    }
    #pragma unroll
    for (int d = 0; d < 8; ++d)
      s_dt[d*SD + t] = softplusf(fmaf(dtpw[d], dtr, dtpb[d]));
  }
  __syncthreads();

  // ---- step C: per-(d,s) scan over the chunk, unrolled x4, DPP reduction
  if (tid < 128){
    const int d = tid >> 4, s = tid & 15;
    const float Ads = -expf(Alog[(d << 4) + s]);
    float h = 0.f;
    if constexpr (FINAL) h = hin[((size_t)b * NCH + c) * 128 + tid];
    const float* pdt = s_dt + d*SD;
    const float* pxm = s_xm + d*SD;
    const float* pB  = s_Bv + s*PADT;
    const float* pC  = FINAL ? (s_Cv + s*PADT) : nullptr;
    float sdt = 0.f;
    for (int t0 = 0; t0 < TCH; t0 += 4){
      const float4 dt4 = *reinterpret_cast<const float4*>(pdt + t0);
      const float4 xm4 = *reinterpret_cast<const float4*>(pxm + t0);
      float B0 = pB[t0], B1 = pB[t0+1], B2 = pB[t0+2], B3 = pB[t0+3];
      if constexpr (FINAL){
        float C0 = pC[t0], C1 = pC[t0+1], C2 = pC[t0+2], C3 = pC[t0+3];
        float y0, y1, y2, y3;
        { float dA = __expf(dt4.x*Ads); h = fmaf(dA, h, dt4.x*xm4.x*B0); y0 = h*C0; }
        { float dA = __expf(dt4.y*Ads); h = fmaf(dA, h, dt4.y*xm4.y*B1); y1 = h*C1; }
        { float dA = __expf(dt4.z*Ads); h = fmaf(dA, h, dt4.z*xm4.z*B2); y2 = h*C2; }
        { float dA = __expf(dt4.w*Ads); h = fmaf(dA, h, dt4.w*xm4.w*B3); y3 = h*C3; }
        y0 = red16(y0); y1 = red16(y1); y2 = red16(y2); y3 = red16(y3);
        if (s == 0)
          *reinterpret_cast<float4*>(s_y + d*SY + t0) = make_float4(y0, y1, y2, y3);
      } else {
        sdt += dt4.x + dt4.y + dt4.z + dt4.w;
        { float dA = __expf(dt4.x*Ads); h = fmaf(dA, h, dt4.x*xm4.x*B0); }
        { float dA = __expf(dt4.y*Ads); h = fmaf(dA, h, dt4.y*xm4.y*B1); }
        { float dA = __expf(dt4.z*Ads); h = fmaf(dA, h, dt4.z*xm4.z*B2); }
        { float dA = __expf(dt4.w*Ads); h = fmaf(dA, h, dt4.w*xm4.w*B3); }
      }
    }
    if constexpr (!FINAL){
      const size_t base = ((size_t)b * NCH + c) * 128 + tid;
      chA[base] = __expf(Ads * sdt);    // prod of dA == exp(Ads * sum dt)
      chB[base] = h;
    }
  }

  // ---- step D (FINAL): skip + gate + out_proj + LN -> outbuf[b, i, 0:4]
  if constexpr (FINAL){
    __syncthreads();
    const int t = tid;
    const int i = c0 + t;
    float y[8];
    #pragma unroll
    for (int d = 0; d < 8; ++d)
      y[d] = (s_y[d*SY + t] + s_xm[d*SD + t] * Dp[d]) * s_zs[d*PADT + t];
    float o[4];
    #pragma unroll
    for (int e = 0; e < 4; ++e){
      float acc = opw[e*8] * y[0];
      #pragma unroll
      for (int d = 1; d < 8; ++d) acc = fmaf(opw[e*8+d], y[d], acc);
      o[e] = acc;
    }
    const float mu = 0.25f * (o[0] + o[1] + o[2] + o[3]);
    const float v0 = o[0] - mu, v1 = o[1] - mu, v2 = o[2] - mu, v3 = o[3] - mu;
    const float inv = rsqrtf(0.25f * (v0*v0 + v1*v1 + v2*v2 + v3*v3) + 1e-5f);
    float4 r;
    r.x = fmaf(v0 * inv, lng[0], lnb[0]);
    r.y = fmaf(v1 * inv, lng[1], lnb[1]);
    r.z = fmaf(v2 * inv, lng[2], lnb[2]);
    r.w = fmaf(v3 * inv, lng[3], lnb[3]);
    *reinterpret_cast<float4*>(outbuf + ((size_t)b * LTOT + i) * 4) = r;
  }
}

// ---------------- chunk-prefix combine ----------------
__global__ __launch_bounds__(512) void k_combine(const float* __restrict__ chA,
                                                 const float* __restrict__ chB,
                                                 float* __restrict__ hin){
  const int tb  = threadIdx.x;           // 0..511
  const int b   = tb >> 7;
  const int idx = tb & 127;
  const float* pa = chA + (size_t)b * NCH * 128 + idx;
  const float* pb = chB + (size_t)b * NCH * 128 + idx;
  float*       ph = hin + (size_t)b * NCH * 128 + idx;
  float h = 0.f;
  float a[16], v[16];
  #pragma unroll
  for (int m = 0; m < 16; ++m){ a[m] = pa[m*128]; v[m] = pb[m*128]; }
  for (int c0 = 0; c0 < NCH; c0 += 16){
    float a2[16], v2[16];
    if (c0 + 16 < NCH){
      #pragma unroll
      for (int m = 0; m < 16; ++m){ a2[m] = pa[(c0+16+m)*128]; v2[m] = pb[(c0+16+m)*128]; }
    } else {
      #pragma unroll
      for (int m = 0; m < 16; ++m){ a2[m] = 0.f; v2[m] = 0.f; }
    }
    #pragma unroll
    for (int m = 0; m < 16; ++m){ ph[(c0+m)*128] = h; h = fmaf(a[m], h, v[m]); }
    #pragma unroll
    for (int m = 0; m < 16; ++m){ a[m] = a2[m]; v[m] = v2[m]; }
  }
}

// ---------------- final gather + mean ----------------
__global__ __launch_bounds__(256) void k_final(const float* __restrict__ outbuf,
                                               const int* __restrict__ sp,
                                               float* __restrict__ out){
  const int l = blockIdx.x * 256 + threadIdx.x;   // spatial flat index 0..L-1
  const int b = blockIdx.y;
  const int q0 = rho0(l, sp), q1 = rho1(l, sp);
  const int j  = LTOT - 1 - l;
  const int q2 = rho0(j, sp), q3 = rho1(j, sp);
  const float* ob = outbuf + (size_t)b * LTOT * 4;
  out[(size_t)b * LTOT + l] =
      0.25f * (ob[q0*4 + 0] + ob[q1*4 + 1] + ob[q2*4 + 2] + ob[q3*4 + 3]);
}

extern "C" void kernel_launch(void* const* d_in, const int* in_sizes, int n_in,
                              void* d_out, int out_size, void* d_ws, size_t ws_size,
                              hipStream_t stream) {
  const float* X    = (const float*)d_in[0];   // (4,6,128,128)
  const float* dww  = (const float*)d_in[1];   // (4,1,3)
  const float* dwb  = (const float*)d_in[2];   // (4)
  const float* ipw  = (const float*)d_in[3];   // (16,4)
  const float* c1w  = (const float*)d_in[4];   // (8,1,4)
  const float* c1b  = (const float*)d_in[5];   // (8)
  const float* xpw  = (const float*)d_in[6];   // (33,8)
  const float* dtpw = (const float*)d_in[7];   // (8,1)
  const float* dtpb = (const float*)d_in[8];   // (8)
  const float* Alog = (const float*)d_in[9];   // (8,16)
  const float* Dp   = (const float*)d_in[10];  // (8)
  const float* opw  = (const float*)d_in[11];  // (4,8)
  const float* lng  = (const float*)d_in[12];  // (4)
  const float* lnb  = (const float*)d_in[13];  // (4)
  float* out = (float*)d_out;

  // workspace layout (all fully written before read each call):
  //   [0)           sp      16384 int
  //   [16384)       prefix   8193 int
  //   [24580)       hin     NB*NCH*128 f32          (1 MB)
  //   [24580+hin)   outbuf  NB*LTOT*4  f32          (6.3 MB); chA/chB alias its head:
  //                 chA = outbuf[0 .. NB*NCH*128), chB next — dead before outbuf is written.
  int* wsI    = (int*)d_ws;
  int* sp     = wsI;
  int* prefix = wsI + 16384;
  float* hin    = (float*)(wsI + 24580);
  float* outbuf = hin + (size_t)NB * NCH * 128;
  float* chA    = outbuf;
  float* chB    = outbuf + (size_t)NB * NCH * 128;

  k_hist<<<1, 256, 0, stream>>>(prefix);
  k_rank<<<64, 256, 0, stream>>>(prefix, sp);
  k_chunk<false><<<dim3(NCH, NB), 192, 0, stream>>>(X, dww, dwb, ipw, c1w, c1b, xpw,
      dtpw, dtpb, Alog, Dp, opw, lng, lnb, sp, (const float*)nullptr, chA, chB, (float*)nullptr);
  k_combine<<<1, 512, 0, stream>>>(chA, chB, hin);
  k_chunk<true><<<dim3(NCH, NB), 192, 0, stream>>>(X, dww, dwb, ipw, c1w, c1b, xpw,
      dtpw, dtpb, Alog, Dp, opw, lng, lnb, sp, hin, (float*)nullptr, (float*)nullptr, outbuf);
  k_final<<<dim3(LTOT / 256, NB), 256, 0, stream>>>(outbuf, sp, out);
}

// Round 3
// 236.877 us; speedup vs baseline: 1.6601x; 1.1867x over previous
//
#include <hip/hip_runtime.h>
#include <math.h>

// Problem constants: D_MODEL=4, D_INNER=8, D_STATE=16, D_CONV=4, DT_RANK=1
// x: (B=4, N=6, H=128, W=128) f32. L = 98304.
#define HWSZ  16384
#define LTOT  98304
#define NB    4
#define TCH   96           // chunk length
#define NCH   1024         // LTOT / TCH
#define GCH   64           // chunks per combine group
#define NGRP  16           // NCH / GCH
#define SD    100          // padded t-stride: 100%4==0 (16B-aligned float4), 100%32==4 (2-way max = free)

__device__ __forceinline__ float siluf(float x){ return x / (1.f + expf(-x)); }
__device__ __forceinline__ float softplusf(float x){ return fmaxf(x, 0.f) + log1pf(expf(-fabsf(x))); }

// 16-lane (row-aligned) sum via DPP butterflies — pure VALU, no DS ops.
__device__ __forceinline__ float red16(float x){
  int v;
  v = __float_as_int(x);
  x += __int_as_float(__builtin_amdgcn_update_dpp(0, v, 0xB1, 0xF, 0xF, true));   // quad_perm xor1
  v = __float_as_int(x);
  x += __int_as_float(__builtin_amdgcn_update_dpp(0, v, 0x4E, 0xF, 0xF, true));   // quad_perm xor2
  v = __float_as_int(x);
  x += __int_as_float(__builtin_amdgcn_update_dpp(0, v, 0x141, 0xF, 0xF, true));  // row_half_mirror
  v = __float_as_int(x);
  x += __int_as_float(__builtin_amdgcn_update_dpp(0, v, 0x140, 0xF, 0xF, true));  // row_mirror
  return x;
}

// perm k=0 (scanA): i = n*HW + r -> spatial n*HW + sp[r]
__device__ __forceinline__ int rho0(int i, const int* __restrict__ sp){
  int n = i >> 14; int r = i & (HWSZ - 1);
  return (n << 14) + sp[r];
}
// perm k=1 (scanB): i = r*6 + n ; tid = (r even ? n : 5-n) -> tid*HW + sp[r]
__device__ __forceinline__ int rho1(int i, const int* __restrict__ sp){
  unsigned ui = (unsigned)i;
  unsigned r = ui / 6u; unsigned n = ui - r * 6u;
  unsigned t = (r & 1u) ? (5u - n) : n;
  return (int)((t << 14) + (unsigned)sp[r]);
}
// k=2 is rho0(L-1-i), k=3 is rho1(L-1-i)

// ---------------- perm build: stable argsort of d2 over 128x128 ----------------
__global__ __launch_bounds__(256) void k_hist(int* __restrict__ prefix){
  __shared__ int hist[8193];
  __shared__ int part[256];
  const int tid = threadIdx.x;
  for (int v = tid; v < 8193; v += 256) hist[v] = 0;
  __syncthreads();
  for (int j = tid; j < HWSZ; j += 256){
    int dy = (j >> 7) - 64, dx = (j & 127) - 64;
    atomicAdd(&hist[dy*dy + dx*dx], 1);
  }
  __syncthreads();
  const int base = tid * 33;
  int sum = 0;
  for (int m = 0; m < 33; ++m){ int v = base + m; if (v < 8193) sum += hist[v]; }
  part[tid] = sum;
  __syncthreads();
  if (tid == 0){
    int run = 0;
    for (int t = 0; t < 256; ++t){ int c = part[t]; part[t] = run; run += c; }
  }
  __syncthreads();
  int run = part[tid];
  for (int m = 0; m < 33; ++m){
    int v = base + m;
    if (v < 8193){ int c = hist[v]; prefix[v] = run; run += c; }
  }
}

__global__ __launch_bounds__(256) void k_rank(const int* __restrict__ prefix, int* __restrict__ sp){
  const int j = blockIdx.x * 256 + threadIdx.x;   // 0..16383
  const int y = j >> 7, x = j & 127;
  const int dy = y - 64, dx = x - 64;
  const int v = dy*dy + dx*dx;
  int cnt = prefix[v];                            // elements with smaller d2
  for (int yp = 0; yp < y; ++yp){
    int dyp = yp - 64;
    int tt = v - dyp*dyp;
    if (tt < 0) continue;
    int rr = (int)sqrtf((float)tt);
    while (rr * rr > tt) --rr;
    while ((rr + 1) * (rr + 1) <= tt) ++rr;
    if (rr * rr == tt){
      cnt += (rr <= 64) ? 1 : 0;                  // x = 64 - rr
      cnt += (rr >= 1 && rr <= 63) ? 1 : 0;       // x = 64 + rr, distinct
    }
  }
  if (x > 64) cnt += 1;                           // mirror 128-x precedes
  sp[cnt] = j;
}

// ---------------- pass 1: per-chunk pipeline + from-zero scan ----------------
__global__ __launch_bounds__(128)
void k_scan(const float* __restrict__ X,
            const float* __restrict__ dww, const float* __restrict__ dwb,
            const float* __restrict__ ipw,
            const float* __restrict__ c1w, const float* __restrict__ c1b,
            const float* __restrict__ xpw,
            const float* __restrict__ dtpw, const float* __restrict__ dtpb,
            const float* __restrict__ Alog,
            const int* __restrict__ sp,
            float* __restrict__ chA, float* __restrict__ chB,
            float* __restrict__ y0g)
{
  const int c = blockIdx.x, b = blockIdx.y;
  const int c0 = c * TCH;
  const int tid = threadIdx.x;
  const float* Xb = X + (size_t)b * LTOT;

  __shared__ __align__(16) float s_pre[(TCH + 3) * 9];
  __shared__ __align__(16) float s_dt[8 * SD];
  __shared__ __align__(16) float s_xm[8 * SD];
  __shared__ __align__(16) float s_Bv[16 * SD];
  __shared__ __align__(16) float s_Cv[16 * SD];

  // ---- step A: 12 gathers -> dwconv+silu -> in_proj (xm half only)
  if (tid < TCH + 3){
    const int m = tid;
    const int i = c0 - 3 + m;
    if (i < 0){
      #pragma unroll
      for (int d = 0; d < 8; ++d) s_pre[m*9 + d] = 0.f;
    } else {
      const int i2 = LTOT - 1 - i;
      const bool okm = (i > 0), okp = (i < LTOT - 1);
      int q[12];
      q[0]  = okm ? rho0(i - 1, sp) : 0;
      q[1]  =       rho0(i,     sp);
      q[2]  = okp ? rho0(i + 1, sp) : 0;
      q[3]  = okm ? rho1(i - 1, sp) : 0;
      q[4]  =       rho1(i,     sp);
      q[5]  = okp ? rho1(i + 1, sp) : 0;
      q[6]  = okm ? rho0(i2 + 1, sp) : 0;
      q[7]  =       rho0(i2,     sp);
      q[8]  = okp ? rho0(i2 - 1, sp) : 0;
      q[9]  = okm ? rho1(i2 + 1, sp) : 0;
      q[10] =       rho1(i2,     sp);
      q[11] = okp ? rho1(i2 - 1, sp) : 0;
      float xv[12];
      #pragma unroll
      for (int t = 0; t < 12; ++t) xv[t] = Xb[q[t]];
      if (!okm){ xv[0] = 0.f; xv[3] = 0.f; xv[6] = 0.f; xv[9]  = 0.f; }
      if (!okp){ xv[2] = 0.f; xv[5] = 0.f; xv[8] = 0.f; xv[11] = 0.f; }
      float u[4];
      #pragma unroll
      for (int k = 0; k < 4; ++k){
        float acc = dwb[k];
        acc = fmaf(dww[k*3+0], xv[k*3+0], acc);
        acc = fmaf(dww[k*3+1], xv[k*3+1], acc);
        acc = fmaf(dww[k*3+2], xv[k*3+2], acc);
        u[k] = siluf(acc);
      }
      #pragma unroll
      for (int d = 0; d < 8; ++d){
        float acc =      ipw[d*4+0] * u[0];
        acc = fmaf(ipw[d*4+1], u[1], acc);
        acc = fmaf(ipw[d*4+2], u[2], acc);
        acc = fmaf(ipw[d*4+3], u[3], acc);
        s_pre[m*9 + d] = acc;
      }
    }
  }
  __syncthreads();

  // ---- step B: causal conv4+silu -> xm ; x_proj -> dt, B, C
  if (tid < TCH){
    const int t = tid;
    float xm[8];
    #pragma unroll
    for (int d = 0; d < 8; ++d){
      float acc = c1b[d];
      #pragma unroll
      for (int tau = 0; tau < 4; ++tau)
        acc = fmaf(c1w[d*4+tau], s_pre[(t+tau)*9 + d], acc);
      float v = siluf(acc);
      xm[d] = v;
      s_xm[d*SD + t] = v;
    }
    float dtr = xpw[0] * xm[0];
    #pragma unroll
    for (int d = 1; d < 8; ++d) dtr = fmaf(xpw[d], xm[d], dtr);
    #pragma unroll
    for (int s = 0; s < 16; ++s){
      float acc = xpw[(1+s)*8] * xm[0];
      #pragma unroll
      for (int d = 1; d < 8; ++d) acc = fmaf(xpw[(1+s)*8+d], xm[d], acc);
      s_Bv[s*SD + t] = acc;
      float acc2 = xpw[(17+s)*8] * xm[0];
      #pragma unroll
      for (int d = 1; d < 8; ++d) acc2 = fmaf(xpw[(17+s)*8+d], xm[d], acc2);
      s_Cv[s*SD + t] = acc2;
    }
    #pragma unroll
    for (int d = 0; d < 8; ++d)
      s_dt[d*SD + t] = softplusf(fmaf(dtpw[d], dtr, dtpb[d]));
  }
  __syncthreads();

  // ---- step C: from-zero scan; emit y0 (s==0 lanes), chunk summary
  {
    const int d = tid >> 4, s = tid & 15;
    const float Ads = -expf(Alog[tid]);     // tid == d*16+s
    float h = 0.f, sdt = 0.f;
    const float* pdt = s_dt + d*SD;
    const float* pxm = s_xm + d*SD;
    const float* pB  = s_Bv + s*SD;
    const float* pC  = s_Cv + s*SD;
    float* yb = y0g + ((size_t)b * NCH + c) * 768 + d * 96;
    for (int t0 = 0; t0 < TCH; t0 += 4){
      const float4 dt4 = *reinterpret_cast<const float4*>(pdt + t0);
      const float4 xm4 = *reinterpret_cast<const float4*>(pxm + t0);
      const float4 B4  = *reinterpret_cast<const float4*>(pB + t0);
      const float4 C4  = *reinterpret_cast<const float4*>(pC + t0);
      sdt += dt4.x + dt4.y + dt4.z + dt4.w;
      float y0, y1, y2, y3;
      { float dA = __expf(dt4.x*Ads); h = fmaf(dA, h, dt4.x*xm4.x*B4.x); y0 = h*C4.x; }
      { float dA = __expf(dt4.y*Ads); h = fmaf(dA, h, dt4.y*xm4.y*B4.y); y1 = h*C4.y; }
      { float dA = __expf(dt4.z*Ads); h = fmaf(dA, h, dt4.z*xm4.z*B4.z); y2 = h*C4.z; }
      { float dA = __expf(dt4.w*Ads); h = fmaf(dA, h, dt4.w*xm4.w*B4.w); y3 = h*C4.w; }
      y0 = red16(y0); y1 = red16(y1); y2 = red16(y2); y3 = red16(y3);
      if (s == 0)
        *reinterpret_cast<float4*>(yb + t0) = make_float4(y0, y1, y2, y3);
    }
    const size_t base = ((size_t)b * NCH + c) * 128 + tid;
    chA[base] = __expf(Ads * sdt);          // product of dA over the chunk
    chB[base] = h;
  }
}

// ---------------- combine level 1: per-group prefixes ----------------
__global__ __launch_bounds__(128) void k_comb1(const float* __restrict__ chA,
                                               const float* __restrict__ chB,
                                               float* __restrict__ hpre,
                                               float* __restrict__ apre,
                                               float* __restrict__ GA,
                                               float* __restrict__ GB){
  const int j = blockIdx.x;              // 0..63
  const int g = j >> 2, b = j & 3;
  const int idx = threadIdx.x;           // 0..127
  const size_t base = ((size_t)b * NCH + (size_t)g * GCH) * 128 + idx;
  float h = 0.f, a = 1.f;
  float A_[8], B_[8];
  #pragma unroll
  for (int m = 0; m < 8; ++m){ A_[m] = chA[base + (size_t)m*128]; B_[m] = chB[base + (size_t)m*128]; }
  for (int cc = 0; cc < GCH; cc += 8){
    float A2[8], B2[8];
    if (cc + 8 < GCH){
      #pragma unroll
      for (int m = 0; m < 8; ++m){ A2[m] = chA[base + (size_t)(cc+8+m)*128]; B2[m] = chB[base + (size_t)(cc+8+m)*128]; }
    } else {
      #pragma unroll
      for (int m = 0; m < 8; ++m){ A2[m] = 0.f; B2[m] = 0.f; }
    }
    #pragma unroll
    for (int m = 0; m < 8; ++m){
      hpre[base + (size_t)(cc+m)*128] = h;
      apre[base + (size_t)(cc+m)*128] = a;
      h = fmaf(A_[m], h, B_[m]);
      a *= A_[m];
    }
    #pragma unroll
    for (int m = 0; m < 8; ++m){ A_[m] = A2[m]; B_[m] = B2[m]; }
  }
  GA[(size_t)(g*4+b)*128 + idx] = a;
  GB[(size_t)(g*4+b)*128 + idx] = h;
}

// ---------------- combine level 2: group-boundary prefixes ----------------
__global__ __launch_bounds__(512) void k_comb2(const float* __restrict__ GA,
                                               const float* __restrict__ GB,
                                               float* __restrict__ Hg){
  const int tid = threadIdx.x;           // chain 0..511 (= b*128+idx)
  float a[NGRP], v[NGRP];
  #pragma unroll
  for (int g = 0; g < NGRP; ++g){ a[g] = GA[(size_t)g*512 + tid]; v[g] = GB[(size_t)g*512 + tid]; }
  float h = 0.f;
  #pragma unroll
  for (int g = 0; g < NGRP; ++g){
    Hg[(size_t)g*512 + tid] = h;
    h = fmaf(a[g], h, v[g]);
  }
}

// ---------------- pass 2: correction + epilogue (no serial chain) ----------------
__global__ __launch_bounds__(128)
void k_corr(const float* __restrict__ X,
            const float* __restrict__ dww, const float* __restrict__ dwb,
            const float* __restrict__ ipw,
            const float* __restrict__ c1w, const float* __restrict__ c1b,
            const float* __restrict__ xpw,
            const float* __restrict__ dtpw, const float* __restrict__ dtpb,
            const float* __restrict__ Alog, const float* __restrict__ Dp,
            const float* __restrict__ opw,
            const float* __restrict__ lng, const float* __restrict__ lnb,
            const int* __restrict__ sp,
            const float* __restrict__ hpre, const float* __restrict__ apre,
            const float* __restrict__ Hg,
            const float* __restrict__ y0g,
            float* __restrict__ outbuf)
{
  const int c = blockIdx.x, b = blockIdx.y;
  const int c0 = c * TCH;
  const int tid = threadIdx.x;
  const float* Xb = X + (size_t)b * LTOT;
  const size_t cb = (size_t)b * NCH + c;

  // hoist h_in assembly loads (consumed much later)
  const float hp = hpre[cb * 128 + tid];
  const float ap = apre[cb * 128 + tid];
  const float Hv = Hg[(size_t)(c >> 6) * 512 + (size_t)b * 128 + tid];
  const float hin = fmaf(ap, Hv, hp);

  __shared__ __align__(16) float s_pre[(TCH + 3) * 9];   // reused as s_yf (stride SD, 800 <= 891)
  __shared__ __align__(16) float s_dt[8 * SD];
  __shared__ __align__(16) float s_xm[8 * SD];
  __shared__ __align__(16) float s_Cv[16 * SD];
  __shared__ __align__(16) float s_zs[8 * SD];
  __shared__ __align__(16) float s_sg[8 * SD];
  float* s_yf = s_pre;

  // ---- step A (with z gate)
  if (tid < TCH + 3){
    const int m = tid;
    const int i = c0 - 3 + m;
    if (i < 0){
      #pragma unroll
      for (int d = 0; d < 8; ++d) s_pre[m*9 + d] = 0.f;
    } else {
      const int i2 = LTOT - 1 - i;
      const bool okm = (i > 0), okp = (i < LTOT - 1);
      int q[12];
      q[0]  = okm ? rho0(i - 1, sp) : 0;
      q[1]  =       rho0(i,     sp);
      q[2]  = okp ? rho0(i + 1, sp) : 0;
      q[3]  = okm ? rho1(i - 1, sp) : 0;
      q[4]  =       rho1(i,     sp);
      q[5]  = okp ? rho1(i + 1, sp) : 0;
      q[6]  = okm ? rho0(i2 + 1, sp) : 0;
      q[7]  =       rho0(i2,     sp);
      q[8]  = okp ? rho0(i2 - 1, sp) : 0;
      q[9]  = okm ? rho1(i2 + 1, sp) : 0;
      q[10] =       rho1(i2,     sp);
      q[11] = okp ? rho1(i2 - 1, sp) : 0;
      float xv[12];
      #pragma unroll
      for (int t = 0; t < 12; ++t) xv[t] = Xb[q[t]];
      if (!okm){ xv[0] = 0.f; xv[3] = 0.f; xv[6] = 0.f; xv[9]  = 0.f; }
      if (!okp){ xv[2] = 0.f; xv[5] = 0.f; xv[8] = 0.f; xv[11] = 0.f; }
      float u[4];
      #pragma unroll
      for (int k = 0; k < 4; ++k){
        float acc = dwb[k];
        acc = fmaf(dww[k*3+0], xv[k*3+0], acc);
        acc = fmaf(dww[k*3+1], xv[k*3+1], acc);
        acc = fmaf(dww[k*3+2], xv[k*3+2], acc);
        u[k] = siluf(acc);
      }
      #pragma unroll
      for (int d = 0; d < 8; ++d){
        float acc =      ipw[d*4+0] * u[0];
        acc = fmaf(ipw[d*4+1], u[1], acc);
        acc = fmaf(ipw[d*4+2], u[2], acc);
        acc = fmaf(ipw[d*4+3], u[3], acc);
        s_pre[m*9 + d] = acc;
      }
      if (m >= 3){
        const int t0 = m - 3;
        #pragma unroll
        for (int d = 0; d < 8; ++d){
          float acc =      ipw[(8+d)*4+0] * u[0];
          acc = fmaf(ipw[(8+d)*4+1], u[1], acc);
          acc = fmaf(ipw[(8+d)*4+2], u[2], acc);
          acc = fmaf(ipw[(8+d)*4+3], u[3], acc);
          s_zs[d*SD + t0] = siluf(acc);
        }
      }
    }
  }
  __syncthreads();

  // ---- step B: xm, dt, C (no B needed)
  if (tid < TCH){
    const int t = tid;
    float xm[8];
    #pragma unroll
    for (int d = 0; d < 8; ++d){
      float acc = c1b[d];
      #pragma unroll
      for (int tau = 0; tau < 4; ++tau)
        acc = fmaf(c1w[d*4+tau], s_pre[(t+tau)*9 + d], acc);
      float v = siluf(acc);
      xm[d] = v;
      s_xm[d*SD + t] = v;
    }
    float dtr = xpw[0] * xm[0];
    #pragma unroll
    for (int d = 1; d < 8; ++d) dtr = fmaf(xpw[d], xm[d], dtr);
    #pragma unroll
    for (int s = 0; s < 16; ++s){
      float acc2 = xpw[(17+s)*8] * xm[0];
      #pragma unroll
      for (int d = 1; d < 8; ++d) acc2 = fmaf(xpw[(17+s)*8+d], xm[d], acc2);
      s_Cv[s*SD + t] = acc2;
    }
    #pragma unroll
    for (int d = 0; d < 8; ++d)
      s_dt[d*SD + t] = softplusf(fmaf(dtpw[d], dtr, dtpb[d]));
  }
  __syncthreads();

  // ---- inclusive cumsum of dt along t (8 serial lanes, float4 reads)
  if (tid < 8){
    const float* pd = s_dt + tid*SD;
    float* ps = s_sg + tid*SD;
    float run = 0.f;
    for (int t0 = 0; t0 < TCH; t0 += 4){
      const float4 d4 = *reinterpret_cast<const float4*>(pd + t0);
      float r0 = run + d4.x, r1 = r0 + d4.y, r2 = r1 + d4.z, r3 = r2 + d4.w;
      *reinterpret_cast<float4*>(ps + t0) = make_float4(r0, r1, r2, r3);
      run = r3;
    }
  }
  __syncthreads();

  // ---- correction: y = y0 + sum_s C * exp(A*sigma) * h_in   (no carried chain)
  {
    const int d = tid >> 4, s = tid & 15;
    const float Ads = -expf(Alog[tid]);
    const float* psg = s_sg + d*SD;
    const float* pC  = s_Cv + s*SD;
    const float* yb  = y0g + cb * 768 + d * 96;
    for (int t0 = 0; t0 < TCH; t0 += 4){
      const float4 sg4 = *reinterpret_cast<const float4*>(psg + t0);
      const float4 C4  = *reinterpret_cast<const float4*>(pC + t0);
      float4 y04 = make_float4(0.f, 0.f, 0.f, 0.f);
      if (s == 0) y04 = *reinterpret_cast<const float4*>(yb + t0);
      float yc0 = __expf(sg4.x * Ads) * C4.x * hin;
      float yc1 = __expf(sg4.y * Ads) * C4.y * hin;
      float yc2 = __expf(sg4.z * Ads) * C4.z * hin;
      float yc3 = __expf(sg4.w * Ads) * C4.w * hin;
      yc0 = red16(yc0); yc1 = red16(yc1); yc2 = red16(yc2); yc3 = red16(yc3);
      if (s == 0)
        *reinterpret_cast<float4*>(s_yf + d*SD + t0) =
            make_float4(y04.x + yc0, y04.y + yc1, y04.z + yc2, y04.w + yc3);
    }
  }
  __syncthreads();

  // ---- epilogue: skip + gate + out_proj + LN
  if (tid < TCH){
    const int t = tid;
    const int i = c0 + t;
    float y[8];
    #pragma unroll
    for (int d = 0; d < 8; ++d)
      y[d] = (s_yf[d*SD + t] + s_xm[d*SD + t] * Dp[d]) * s_zs[d*SD + t];
    float o[4];
    #pragma unroll
    for (int e = 0; e < 4; ++e){
      float acc = opw[e*8] * y[0];
      #pragma unroll
      for (int d = 1; d < 8; ++d) acc = fmaf(opw[e*8+d], y[d], acc);
      o[e] = acc;
    }
    const float mu = 0.25f * (o[0] + o[1] + o[2] + o[3]);
    const float v0 = o[0] - mu, v1 = o[1] - mu, v2 = o[2] - mu, v3 = o[3] - mu;
    const float inv = rsqrtf(0.25f * (v0*v0 + v1*v1 + v2*v2 + v3*v3) + 1e-5f);
    float4 r;
    r.x = fmaf(v0 * inv, lng[0], lnb[0]);
    r.y = fmaf(v1 * inv, lng[1], lnb[1]);
    r.z = fmaf(v2 * inv, lng[2], lnb[2]);
    r.w = fmaf(v3 * inv, lng[3], lnb[3]);
    *reinterpret_cast<float4*>(outbuf + ((size_t)b * LTOT + i) * 4) = r;
  }
}

// ---------------- final gather + mean ----------------
__global__ __launch_bounds__(256) void k_final(const float* __restrict__ outbuf,
                                               const int* __restrict__ sp,
                                               float* __restrict__ out){
  const int l = blockIdx.x * 256 + threadIdx.x;   // spatial flat index 0..L-1
  const int b = blockIdx.y;
  const int q0 = rho0(l, sp), q1 = rho1(l, sp);
  const int j  = LTOT - 1 - l;
  const int q2 = rho0(j, sp), q3 = rho1(j, sp);
  const float* ob = outbuf + (size_t)b * LTOT * 4;
  out[(size_t)b * LTOT + l] =
      0.25f * (ob[q0*4 + 0] + ob[q1*4 + 1] + ob[q2*4 + 2] + ob[q3*4 + 3]);
}

extern "C" void kernel_launch(void* const* d_in, const int* in_sizes, int n_in,
                              void* d_out, int out_size, void* d_ws, size_t ws_size,
                              hipStream_t stream) {
  const float* X    = (const float*)d_in[0];   // (4,6,128,128)
  const float* dww  = (const float*)d_in[1];   // (4,1,3)
  const float* dwb  = (const float*)d_in[2];   // (4)
  const float* ipw  = (const float*)d_in[3];   // (16,4)
  const float* c1w  = (const float*)d_in[4];   // (8,1,4)
  const float* c1b  = (const float*)d_in[5];   // (8)
  const float* xpw  = (const float*)d_in[6];   // (33,8)
  const float* dtpw = (const float*)d_in[7];   // (8,1)
  const float* dtpb = (const float*)d_in[8];   // (8)
  const float* Alog = (const float*)d_in[9];   // (8,16)
  const float* Dp   = (const float*)d_in[10];  // (8)
  const float* opw  = (const float*)d_in[11];  // (4,8)
  const float* lng  = (const float*)d_in[12];  // (4)
  const float* lnb  = (const float*)d_in[13];  // (4)
  float* out = (float*)d_out;

  // workspace layout (floats unless noted), all rewritten every call:
  //   sp      16384 int
  //   prefix   8193 int (+3 pad)
  //   chA/chB/hpre/apre  4 x 524288        (8 MB)
  //   GA/GB/Hg           3 x 8192
  //   y0g     NB*NCH*768 = 3,145,728       (12.6 MB)
  //   outbuf  NB*LTOT*4  = 1,572,864       (6.3 MB)
  //   total ~ 27.5 MB
  int* wsI    = (int*)d_ws;
  int* sp     = wsI;
  int* prefix = wsI + 16384;
  float* chA  = (float*)(wsI + 24580);
  float* chB  = chA  + 524288;
  float* hpre = chB  + 524288;
  float* apre = hpre + 524288;
  float* GA   = apre + 524288;
  float* GB   = GA + 8192;
  float* Hg   = GB + 8192;
  float* y0g  = Hg + 8192;
  float* outbuf = y0g + 3145728;

  k_hist<<<1, 256, 0, stream>>>(prefix);
  k_rank<<<64, 256, 0, stream>>>(prefix, sp);
  k_scan<<<dim3(NCH, NB), 128, 0, stream>>>(X, dww, dwb, ipw, c1w, c1b, xpw,
      dtpw, dtpb, Alog, sp, chA, chB, y0g);
  k_comb1<<<64, 128, 0, stream>>>(chA, chB, hpre, apre, GA, GB);
  k_comb2<<<1, 512, 0, stream>>>(GA, GB, Hg);
  k_corr<<<dim3(NCH, NB), 128, 0, stream>>>(X, dww, dwb, ipw, c1w, c1b, xpw,
      dtpw, dtpb, Alog, Dp, opw, lng, lnb, sp, hpre, apre, Hg, y0g, outbuf);
  k_final<<<dim3(LTOT / 256, NB), 256, 0, stream>>>(outbuf, sp, out);
}

// Round 4
// 213.268 us; speedup vs baseline: 1.8439x; 1.1107x over previous
//
#include <hip/hip_runtime.h>
#include <math.h>

// Problem constants: D_MODEL=4, D_INNER=8, D_STATE=16, D_CONV=4, DT_RANK=1
// x: (B=4, N=6, H=128, W=128) f32. L = 98304.
#define HWSZ  16384
#define LTOT  98304
#define NB    4
#define TCH   96           // chunk length
#define NCH   1024         // LTOT / TCH
#define GCH   64           // chunks per combine group
#define NGRP  16           // NCH / GCH
#define SD    100          // k_scan t-stride: %4==0 (b128 align), d-offset 4 banks (conflict-free quads)

__device__ __forceinline__ float siluf(float x){ return x / (1.f + expf(-x)); }
__device__ __forceinline__ float softplusf(float x){ return fmaxf(x, 0.f) + log1pf(expf(-fabsf(x))); }

// 16-lane (row-aligned) sum via DPP butterflies — pure VALU, no DS ops.
__device__ __forceinline__ float red16(float x){
  int v;
  v = __float_as_int(x);
  x += __int_as_float(__builtin_amdgcn_update_dpp(0, v, 0xB1, 0xF, 0xF, true));   // quad_perm xor1
  v = __float_as_int(x);
  x += __int_as_float(__builtin_amdgcn_update_dpp(0, v, 0x4E, 0xF, 0xF, true));   // quad_perm xor2
  v = __float_as_int(x);
  x += __int_as_float(__builtin_amdgcn_update_dpp(0, v, 0x141, 0xF, 0xF, true));  // row_half_mirror
  v = __float_as_int(x);
  x += __int_as_float(__builtin_amdgcn_update_dpp(0, v, 0x140, 0xF, 0xF, true));  // row_mirror
  return x;
}

// perm k=0 (scanA): i = n*HW + r -> spatial n*HW + sp[r]
__device__ __forceinline__ int rho0(int i, const int* __restrict__ sp){
  int n = i >> 14; int r = i & (HWSZ - 1);
  return (n << 14) + sp[r];
}
// perm k=1 (scanB): i = r*6 + n ; tid = (r even ? n : 5-n) -> tid*HW + sp[r]
__device__ __forceinline__ int rho1(int i, const int* __restrict__ sp){
  unsigned ui = (unsigned)i;
  unsigned r = ui / 6u; unsigned n = ui - r * 6u;
  unsigned t = (r & 1u) ? (5u - n) : n;
  return (int)((t << 14) + (unsigned)sp[r]);
}
// k=2 is rho0(L-1-i), k=3 is rho1(L-1-i)

// ---------------- perm build: stable argsort of d2 (hist+rank fused, per-block LDS hist) ---
__global__ __launch_bounds__(256) void k_rank(int* __restrict__ sp){
  __shared__ int hist[8193];
  __shared__ int part[256];
  const int tid = threadIdx.x;
  for (int v = tid; v < 8193; v += 256) hist[v] = 0;
  __syncthreads();
  for (int jj = tid; jj < HWSZ; jj += 256){
    int dy = (jj >> 7) - 64, dx = (jj & 127) - 64;
    atomicAdd(&hist[dy*dy + dx*dx], 1);
  }
  __syncthreads();
  const int base = tid * 33;
  {
    int sum = 0;
    for (int m = 0; m < 33; ++m){ int v = base + m; if (v < 8193) sum += hist[v]; }
    part[tid] = sum;
  }
  __syncthreads();
  if (tid == 0){
    int run = 0;
    for (int t = 0; t < 256; ++t){ int c = part[t]; part[t] = run; run += c; }
  }
  __syncthreads();
  {
    int run = part[tid];
    for (int m = 0; m < 33; ++m){
      int v = base + m;
      if (v < 8193){ int c = hist[v]; hist[v] = run; run += c; }   // in-place exclusive prefix
    }
  }
  __syncthreads();

  const int j = blockIdx.x * 256 + tid;           // 0..16383
  const int y = j >> 7, x = j & 127;
  const int dy = y - 64, dx = x - 64;
  const int v = dy*dy + dx*dx;
  int cnt = hist[v];                              // elements with smaller d2
  for (int yp = 0; yp < y; ++yp){
    int dyp = yp - 64;
    int tt = v - dyp*dyp;
    if (tt < 0) continue;
    int rr = (int)sqrtf((float)tt);
    while (rr * rr > tt) --rr;
    while ((rr + 1) * (rr + 1) <= tt) ++rr;
    if (rr * rr == tt){
      cnt += (rr <= 64) ? 1 : 0;                  // x = 64 - rr
      cnt += (rr >= 1 && rr <= 63) ? 1 : 0;       // x = 64 + rr, distinct
    }
  }
  if (x > 64) cnt += 1;                           // mirror 128-x precedes
  sp[cnt] = j;
}

// ---------------- pass 1: per-chunk pipeline + from-zero scan ----------------
__global__ __launch_bounds__(128)
void k_scan(const float* __restrict__ X,
            const float* __restrict__ dww, const float* __restrict__ dwb,
            const float* __restrict__ ipw,
            const float* __restrict__ c1w, const float* __restrict__ c1b,
            const float* __restrict__ xpw,
            const float* __restrict__ dtpw, const float* __restrict__ dtpb,
            const float* __restrict__ Alog,
            const int* __restrict__ sp,
            float* __restrict__ chA, float* __restrict__ chB,
            float* __restrict__ y0g, float4* __restrict__ ug4)
{
  const int c = blockIdx.x, b = blockIdx.y;
  const int c0 = c * TCH;
  const int tid = threadIdx.x;
  const float* Xb = X + (size_t)b * LTOT;

  __shared__ __align__(16) float s_pre[(TCH + 3) * 9];
  __shared__ __align__(16) float s_dt[8 * SD];
  __shared__ __align__(16) float s_dxm[8 * SD];     // dt * xm (s-independent product)
  __shared__ __align__(16) float s_Bv[16 * SD];
  __shared__ __align__(16) float s_Cv[16 * SD];

  // ---- step A: 12 gathers -> dwconv+silu -> u (cached to global) -> in_proj (xm half)
  if (tid < TCH + 3){
    const int m = tid;
    const int i = c0 - 3 + m;
    if (i < 0){
      #pragma unroll
      for (int d = 0; d < 8; ++d) s_pre[m*9 + d] = 0.f;
    } else {
      const int i2 = LTOT - 1 - i;
      const bool okm = (i > 0), okp = (i < LTOT - 1);
      int q[12];
      q[0]  = okm ? rho0(i - 1, sp) : 0;
      q[1]  =       rho0(i,     sp);
      q[2]  = okp ? rho0(i + 1, sp) : 0;
      q[3]  = okm ? rho1(i - 1, sp) : 0;
      q[4]  =       rho1(i,     sp);
      q[5]  = okp ? rho1(i + 1, sp) : 0;
      q[6]  = okm ? rho0(i2 + 1, sp) : 0;
      q[7]  =       rho0(i2,     sp);
      q[8]  = okp ? rho0(i2 - 1, sp) : 0;
      q[9]  = okm ? rho1(i2 + 1, sp) : 0;
      q[10] =       rho1(i2,     sp);
      q[11] = okp ? rho1(i2 - 1, sp) : 0;
      float xv[12];
      #pragma unroll
      for (int t = 0; t < 12; ++t) xv[t] = Xb[q[t]];
      if (!okm){ xv[0] = 0.f; xv[3] = 0.f; xv[6] = 0.f; xv[9]  = 0.f; }
      if (!okp){ xv[2] = 0.f; xv[5] = 0.f; xv[8] = 0.f; xv[11] = 0.f; }
      float u[4];
      #pragma unroll
      for (int k = 0; k < 4; ++k){
        float acc = dwb[k];
        acc = fmaf(dww[k*3+0], xv[k*3+0], acc);
        acc = fmaf(dww[k*3+1], xv[k*3+1], acc);
        acc = fmaf(dww[k*3+2], xv[k*3+2], acc);
        u[k] = siluf(acc);
      }
      ug4[(size_t)b * LTOT + i] = make_float4(u[0], u[1], u[2], u[3]);  // halo double-writes identical
      #pragma unroll
      for (int d = 0; d < 8; ++d){
        float acc =      ipw[d*4+0] * u[0];
        acc = fmaf(ipw[d*4+1], u[1], acc);
        acc = fmaf(ipw[d*4+2], u[2], acc);
        acc = fmaf(ipw[d*4+3], u[3], acc);
        s_pre[m*9 + d] = acc;
      }
    }
  }
  __syncthreads();

  // ---- step B: causal conv4+silu -> xm ; x_proj -> dt, B, C ; store dt and dt*xm
  if (tid < TCH){
    const int t = tid;
    float xm[8];
    #pragma unroll
    for (int d = 0; d < 8; ++d){
      float acc = c1b[d];
      #pragma unroll
      for (int tau = 0; tau < 4; ++tau)
        acc = fmaf(c1w[d*4+tau], s_pre[(t+tau)*9 + d], acc);
      xm[d] = siluf(acc);
    }
    float dtr = xpw[0] * xm[0];
    #pragma unroll
    for (int d = 1; d < 8; ++d) dtr = fmaf(xpw[d], xm[d], dtr);
    #pragma unroll
    for (int s = 0; s < 16; ++s){
      float acc = xpw[(1+s)*8] * xm[0];
      #pragma unroll
      for (int d = 1; d < 8; ++d) acc = fmaf(xpw[(1+s)*8+d], xm[d], acc);
      s_Bv[s*SD + t] = acc;
      float acc2 = xpw[(17+s)*8] * xm[0];
      #pragma unroll
      for (int d = 1; d < 8; ++d) acc2 = fmaf(xpw[(17+s)*8+d], xm[d], acc2);
      s_Cv[s*SD + t] = acc2;
    }
    #pragma unroll
    for (int d = 0; d < 8; ++d){
      float dtv = softplusf(fmaf(dtpw[d], dtr, dtpb[d]));
      s_dt[d*SD + t]  = dtv;
      s_dxm[d*SD + t] = dtv * xm[d];
    }
  }
  __syncthreads();

  // ---- step C: from-zero scan; emit y0 (s==0 lanes), chunk summary
  {
    const int d = tid >> 4, s = tid & 15;
    const float Ads = -expf(Alog[tid]);     // tid == d*16+s
    float h = 0.f, sdt = 0.f;
    const float* pdt = s_dt + d*SD;
    const float* pdx = s_dxm + d*SD;
    const float* pB  = s_Bv + s*SD;
    const float* pC  = s_Cv + s*SD;
    float* yb = y0g + ((size_t)b * NCH + c) * 768 + d * 96;
    for (int t0 = 0; t0 < TCH; t0 += 4){
      const float4 dt4 = *reinterpret_cast<const float4*>(pdt + t0);
      const float4 dx4 = *reinterpret_cast<const float4*>(pdx + t0);
      const float4 B4  = *reinterpret_cast<const float4*>(pB + t0);
      const float4 C4  = *reinterpret_cast<const float4*>(pC + t0);
      sdt += dt4.x + dt4.y + dt4.z + dt4.w;
      float y0, y1, y2, y3;
      { float dA = __expf(dt4.x*Ads); h = fmaf(dA, h, dx4.x*B4.x); y0 = h*C4.x; }
      { float dA = __expf(dt4.y*Ads); h = fmaf(dA, h, dx4.y*B4.y); y1 = h*C4.y; }
      { float dA = __expf(dt4.z*Ads); h = fmaf(dA, h, dx4.z*B4.z); y2 = h*C4.z; }
      { float dA = __expf(dt4.w*Ads); h = fmaf(dA, h, dx4.w*B4.w); y3 = h*C4.w; }
      y0 = red16(y0); y1 = red16(y1); y2 = red16(y2); y3 = red16(y3);
      if (s == 0)
        *reinterpret_cast<float4*>(yb + t0) = make_float4(y0, y1, y2, y3);
    }
    const size_t base = ((size_t)b * NCH + c) * 128 + tid;
    chA[base] = __expf(Ads * sdt);          // product of dA over the chunk
    chB[base] = h;
  }
}

// ---------------- combine level 1: per-group prefixes ----------------
__global__ __launch_bounds__(128) void k_comb1(const float* __restrict__ chA,
                                               const float* __restrict__ chB,
                                               float* __restrict__ hpre,
                                               float* __restrict__ apre,
                                               float* __restrict__ GA,
                                               float* __restrict__ GB){
  const int j = blockIdx.x;              // 0..63
  const int g = j >> 2, b = j & 3;
  const int idx = threadIdx.x;           // 0..127
  const size_t base = ((size_t)b * NCH + (size_t)g * GCH) * 128 + idx;
  float h = 0.f, a = 1.f;
  float A_[8], B_[8];
  #pragma unroll
  for (int m = 0; m < 8; ++m){ A_[m] = chA[base + (size_t)m*128]; B_[m] = chB[base + (size_t)m*128]; }
  for (int cc = 0; cc < GCH; cc += 8){
    float A2[8], B2[8];
    if (cc + 8 < GCH){
      #pragma unroll
      for (int m = 0; m < 8; ++m){ A2[m] = chA[base + (size_t)(cc+8+m)*128]; B2[m] = chB[base + (size_t)(cc+8+m)*128]; }
    } else {
      #pragma unroll
      for (int m = 0; m < 8; ++m){ A2[m] = 0.f; B2[m] = 0.f; }
    }
    #pragma unroll
    for (int m = 0; m < 8; ++m){
      hpre[base + (size_t)(cc+m)*128] = h;
      apre[base + (size_t)(cc+m)*128] = a;
      h = fmaf(A_[m], h, B_[m]);
      a *= A_[m];
    }
    #pragma unroll
    for (int m = 0; m < 8; ++m){ A_[m] = A2[m]; B_[m] = B2[m]; }
  }
  GA[(size_t)(g*4+b)*128 + idx] = a;
  GB[(size_t)(g*4+b)*128 + idx] = h;
}

// ---------------- pass 2: correction + epilogue (no serial chain, no gathers) ----------------
// LDS strides (bank-checked): sg 104 (2-way max), xm/zs/yf 96 (per-instr fixed-d => free),
// Cv 97 (scalar reads, (s+t)%32 distinct).
__global__ __launch_bounds__(128, 4)
void k_corr(const float4* __restrict__ ug4,
            const float* __restrict__ ipw,
            const float* __restrict__ c1w, const float* __restrict__ c1b,
            const float* __restrict__ xpw,
            const float* __restrict__ dtpw, const float* __restrict__ dtpb,
            const float* __restrict__ Alog, const float* __restrict__ Dp,
            const float* __restrict__ opw,
            const float* __restrict__ lng, const float* __restrict__ lnb,
            const float* __restrict__ hpre, const float* __restrict__ apre,
            const float* __restrict__ GA, const float* __restrict__ GB,
            const float* __restrict__ y0g,
            float* __restrict__ outbuf)
{
  const int c = blockIdx.x, b = blockIdx.y;
  const int c0 = c * TCH;
  const int tid = threadIdx.x;
  const size_t cb = (size_t)b * NCH + c;

  __shared__ __align__(16) float s_pre[(TCH + 3) * 9];  // 891 f; reused as s_yf (768 f, stride 96)
  __shared__ __align__(16) float s_sg[8 * 104];         // dt then in-place cumsum -> sigma
  __shared__ __align__(16) float s_xm[8 * 96];
  __shared__ __align__(16) float s_Cv[16 * 97];
  __shared__ __align__(16) float s_zs[8 * 96];
  __shared__ __align__(16) float s_hA[256];             // [0:128) hin, [128:256) Ads
  float* s_yf = s_pre;

  // ---- stage 0: h_in assembly (folds old k_comb2) + per-(d,s) constants to LDS
  {
    const int g = c >> 6;
    const float hp = hpre[cb * 128 + tid];
    const float ap = apre[cb * 128 + tid];
    float Hv = 0.f;
    for (int gp = 0; gp < g; ++gp){
      const float ga = GA[(size_t)gp*512 + (size_t)b*128 + tid];
      const float gb = GB[(size_t)gp*512 + (size_t)b*128 + tid];
      Hv = fmaf(ga, Hv, gb);
    }
    s_hA[tid]       = fmaf(ap, Hv, hp);     // hin[d*16+s]
    s_hA[128 + tid] = -expf(Alog[tid]);     // Ads[d*16+s]
  }

  // ---- stage 1: u-cache load -> in_proj (pre + z gate)
  if (tid < TCH + 3){
    const int m = tid;
    const int i = c0 - 3 + m;
    if (i < 0){
      #pragma unroll
      for (int d = 0; d < 8; ++d) s_pre[m*9 + d] = 0.f;
    } else {
      const float4 u4 = ug4[(size_t)b * LTOT + i];
      const float u[4] = {u4.x, u4.y, u4.z, u4.w};
      #pragma unroll
      for (int d = 0; d < 8; ++d){
        float acc =      ipw[d*4+0] * u[0];
        acc = fmaf(ipw[d*4+1], u[1], acc);
        acc = fmaf(ipw[d*4+2], u[2], acc);
        acc = fmaf(ipw[d*4+3], u[3], acc);
        s_pre[m*9 + d] = acc;
      }
      if (m >= 3){
        const int t0 = m - 3;
        #pragma unroll
        for (int d = 0; d < 8; ++d){
          float acc =      ipw[(8+d)*4+0] * u[0];
          acc = fmaf(ipw[(8+d)*4+1], u[1], acc);
          acc = fmaf(ipw[(8+d)*4+2], u[2], acc);
          acc = fmaf(ipw[(8+d)*4+3], u[3], acc);
          s_zs[d*96 + t0] = siluf(acc);
        }
      }
    }
  }
  __syncthreads();

  // ---- stage 2: conv4+silu -> xm ; dt -> s_sg ; C -> s_Cv
  if (tid < TCH){
    const int t = tid;
    float xm[8];
    #pragma unroll
    for (int d = 0; d < 8; ++d){
      float acc = c1b[d];
      #pragma unroll
      for (int tau = 0; tau < 4; ++tau)
        acc = fmaf(c1w[d*4+tau], s_pre[(t+tau)*9 + d], acc);
      float v = siluf(acc);
      xm[d] = v;
      s_xm[d*96 + t] = v;
    }
    float dtr = xpw[0] * xm[0];
    #pragma unroll
    for (int d = 1; d < 8; ++d) dtr = fmaf(xpw[d], xm[d], dtr);
    #pragma unroll
    for (int s = 0; s < 16; ++s){
      float acc2 = xpw[(17+s)*8] * xm[0];
      #pragma unroll
      for (int d = 1; d < 8; ++d) acc2 = fmaf(xpw[(17+s)*8+d], xm[d], acc2);
      s_Cv[s*97 + t] = acc2;
    }
    #pragma unroll
    for (int d = 0; d < 8; ++d)
      s_sg[d*104 + t] = softplusf(fmaf(dtpw[d], dtr, dtpb[d]));
  }
  __syncthreads();

  // ---- stage 3: in-place inclusive cumsum of dt -> sigma (8 serial lanes)
  if (tid < 8){
    float* ps = s_sg + tid*104;
    float run = 0.f;
    for (int t0 = 0; t0 < TCH; t0 += 4){
      const float4 d4 = *reinterpret_cast<const float4*>(ps + t0);
      float r0 = run + d4.x, r1 = r0 + d4.y, r2 = r1 + d4.z, r3 = r2 + d4.w;
      *reinterpret_cast<float4*>(ps + t0) = make_float4(r0, r1, r2, r3);
      run = r3;
    }
  }
  __syncthreads();

  // ---- stage 4: correction, lanes = (d, tsub), in-register s-accumulation
  {
    const int d = tid >> 4, tsub = tid & 15;
    float w[16], A16[16];
    #pragma unroll
    for (int s = 0; s < 16; ++s){
      w[s]   = s_hA[d*16 + s];
      A16[s] = s_hA[128 + d*16 + s];
    }
    const float* py0 = y0g + cb * 768 + d * 96;
    for (int t = tsub; t < TCH; t += 16){
      const float sg = s_sg[d*104 + t];
      float acc = py0[t];
      #pragma unroll
      for (int s = 0; s < 16; ++s)
        acc = fmaf(s_Cv[s*97 + t], __expf(A16[s] * sg) * w[s], acc);
      s_yf[d*96 + t] = acc;
    }
  }
  __syncthreads();

  // ---- stage 5: epilogue: skip + gate + out_proj + LN
  if (tid < TCH){
    const int t = tid;
    const int i = c0 + t;
    float y[8];
    #pragma unroll
    for (int d = 0; d < 8; ++d)
      y[d] = (s_yf[d*96 + t] + s_xm[d*96 + t] * Dp[d]) * s_zs[d*96 + t];
    float o[4];
    #pragma unroll
    for (int e = 0; e < 4; ++e){
      float acc = opw[e*8] * y[0];
      #pragma unroll
      for (int d = 1; d < 8; ++d) acc = fmaf(opw[e*8+d], y[d], acc);
      o[e] = acc;
    }
    const float mu = 0.25f * (o[0] + o[1] + o[2] + o[3]);
    const float v0 = o[0] - mu, v1 = o[1] - mu, v2 = o[2] - mu, v3 = o[3] - mu;
    const float inv = rsqrtf(0.25f * (v0*v0 + v1*v1 + v2*v2 + v3*v3) + 1e-5f);
    float4 r;
    r.x = fmaf(v0 * inv, lng[0], lnb[0]);
    r.y = fmaf(v1 * inv, lng[1], lnb[1]);
    r.z = fmaf(v2 * inv, lng[2], lnb[2]);
    r.w = fmaf(v3 * inv, lng[3], lnb[3]);
    *reinterpret_cast<float4*>(outbuf + ((size_t)b * LTOT + i) * 4) = r;
  }
}

// ---------------- final gather + mean ----------------
__global__ __launch_bounds__(256) void k_final(const float* __restrict__ outbuf,
                                               const int* __restrict__ sp,
                                               float* __restrict__ out){
  const int l = blockIdx.x * 256 + threadIdx.x;   // spatial flat index 0..L-1
  const int b = blockIdx.y;
  const int q0 = rho0(l, sp), q1 = rho1(l, sp);
  const int j  = LTOT - 1 - l;
  const int q2 = rho0(j, sp), q3 = rho1(j, sp);
  const float* ob = outbuf + (size_t)b * LTOT * 4;
  out[(size_t)b * LTOT + l] =
      0.25f * (ob[q0*4 + 0] + ob[q1*4 + 1] + ob[q2*4 + 2] + ob[q3*4 + 3]);
}

extern "C" void kernel_launch(void* const* d_in, const int* in_sizes, int n_in,
                              void* d_out, int out_size, void* d_ws, size_t ws_size,
                              hipStream_t stream) {
  const float* X    = (const float*)d_in[0];   // (4,6,128,128)
  const float* dww  = (const float*)d_in[1];   // (4,1,3)
  const float* dwb  = (const float*)d_in[2];   // (4)
  const float* ipw  = (const float*)d_in[3];   // (16,4)
  const float* c1w  = (const float*)d_in[4];   // (8,1,4)
  const float* c1b  = (const float*)d_in[5];   // (8)
  const float* xpw  = (const float*)d_in[6];   // (33,8)
  const float* dtpw = (const float*)d_in[7];   // (8,1)
  const float* dtpb = (const float*)d_in[8];   // (8)
  const float* Alog = (const float*)d_in[9];   // (8,16)
  const float* Dp   = (const float*)d_in[10];  // (8)
  const float* opw  = (const float*)d_in[11];  // (4,8)
  const float* lng  = (const float*)d_in[12];  // (4)
  const float* lnb  = (const float*)d_in[13];  // (4)
  float* out = (float*)d_out;

  // workspace layout (all rewritten every call):
  //   sp      16384 int                          (64 KB)
  //   chA/chB/hpre/apre  4 x 524288 f32          (8 MB)
  //   GA/GB              2 x 8192 f32
  //   ug      NB*LTOT float4 = 1,572,864 f32     (6.3 MB)
  //   y0g     NB*NCH*768    = 3,145,728 f32      (12.6 MB)
  //   outbuf  NB*LTOT*4     = 1,572,864 f32      (6.3 MB)
  //   total ~ 33.4 MB
  int* wsI    = (int*)d_ws;
  int* sp     = wsI;
  float* chA  = (float*)(wsI + 16384);
  float* chB  = chA  + 524288;
  float* hpre = chB  + 524288;
  float* apre = hpre + 524288;
  float* GA   = apre + 524288;
  float* GB   = GA + 8192;
  float4* ug4 = (float4*)(GB + 8192);
  float* y0g  = (float*)(ug4) + (size_t)NB * LTOT * 4;
  float* outbuf = y0g + 3145728;

  k_rank<<<64, 256, 0, stream>>>(sp);
  k_scan<<<dim3(NCH, NB), 128, 0, stream>>>(X, dww, dwb, ipw, c1w, c1b, xpw,
      dtpw, dtpb, Alog, sp, chA, chB, y0g, ug4);
  k_comb1<<<64, 128, 0, stream>>>(chA, chB, hpre, apre, GA, GB);
  k_corr<<<dim3(NCH, NB), 128, 0, stream>>>(ug4, ipw, c1w, c1b, xpw,
      dtpw, dtpb, Alog, Dp, opw, lng, lnb, hpre, apre, GA, GB, y0g, outbuf);
  k_final<<<dim3(LTOT / 256, NB), 256, 0, stream>>>(outbuf, sp, out);
}

// Round 5
// 184.391 us; speedup vs baseline: 2.1327x; 1.1566x over previous
//
#include <hip/hip_runtime.h>
#include <math.h>

// Problem constants: D_MODEL=4, D_INNER=8, D_STATE=16, D_CONV=4, DT_RANK=1
// x: (B=4, N=6, H=128, W=128) f32. L = 98304.
#define HWSZ  16384
#define LTOT  98304
#define NB    4
#define TCH   96           // chunk length
#define NCH   1024         // LTOT / TCH
#define GCH   64           // chunks per combine group
#define NGRP  16           // NCH / GCH
#define SD    100          // k_scan t-stride: %4==0 (b128 align), d-offset 4 banks (conflict-free quads)

// fast transcendentals: v_exp/v_log/v_rcp based; rel err ~1e-7, budget 2.7e-4
__device__ __forceinline__ float siluf(float x){
  return x * __builtin_amdgcn_rcpf(1.f + __expf(-x));
}
__device__ __forceinline__ float softplusf(float x){
  return fmaxf(x, 0.f) + __logf(1.f + __expf(-fabsf(x)));
}

// 16-lane (row-aligned) sum via DPP butterflies — pure VALU, no DS ops.
__device__ __forceinline__ float red16(float x){
  int v;
  v = __float_as_int(x);
  x += __int_as_float(__builtin_amdgcn_update_dpp(0, v, 0xB1, 0xF, 0xF, true));   // quad_perm xor1
  v = __float_as_int(x);
  x += __int_as_float(__builtin_amdgcn_update_dpp(0, v, 0x4E, 0xF, 0xF, true));   // quad_perm xor2
  v = __float_as_int(x);
  x += __int_as_float(__builtin_amdgcn_update_dpp(0, v, 0x141, 0xF, 0xF, true));  // row_half_mirror
  v = __float_as_int(x);
  x += __int_as_float(__builtin_amdgcn_update_dpp(0, v, 0x140, 0xF, 0xF, true));  // row_mirror
  return x;
}

// perm k=0 (scanA): i = n*HW + r -> spatial n*HW + sp[r]
__device__ __forceinline__ int rho0(int i, const int* __restrict__ sp){
  int n = i >> 14; int r = i & (HWSZ - 1);
  return (n << 14) + sp[r];
}
// perm k=1 (scanB): i = r*6 + n ; tid = (r even ? n : 5-n) -> tid*HW + sp[r]
__device__ __forceinline__ int rho1(int i, const int* __restrict__ sp){
  unsigned ui = (unsigned)i;
  unsigned r = ui / 6u; unsigned n = ui - r * 6u;
  unsigned t = (r & 1u) ? (5u - n) : n;
  return (int)((t << 14) + (unsigned)sp[r]);
}
// k=2 is rho0(L-1-i), k=3 is rho1(L-1-i)

// ---------------- perm build: stable argsort of d2 (hist+rank fused) ----------------
__global__ __launch_bounds__(256) void k_rank(int* __restrict__ sp){
  __shared__ int hist[8193];
  __shared__ int part[256];
  const int tid = threadIdx.x;
  for (int v = tid; v < 8193; v += 256) hist[v] = 0;
  __syncthreads();
  for (int jj = tid; jj < HWSZ; jj += 256){
    int dy = (jj >> 7) - 64, dx = (jj & 127) - 64;
    atomicAdd(&hist[dy*dy + dx*dx], 1);
  }
  __syncthreads();
  const int base = tid * 33;
  {
    int sum = 0;
    for (int m = 0; m < 33; ++m){ int v = base + m; if (v < 8193) sum += hist[v]; }
    part[tid] = sum;
  }
  __syncthreads();
  if (tid == 0){
    int run = 0;
    for (int t = 0; t < 256; ++t){ int c = part[t]; part[t] = run; run += c; }
  }
  __syncthreads();
  {
    int run = part[tid];
    for (int m = 0; m < 33; ++m){
      int v = base + m;
      if (v < 8193){ int c = hist[v]; hist[v] = run; run += c; }   // in-place exclusive prefix
    }
  }
  __syncthreads();

  const int j = blockIdx.x * 256 + tid;           // 0..16383
  const int y = j >> 7, x = j & 127;
  const int dy = y - 64, dx = x - 64;
  const int v = dy*dy + dx*dx;
  int cnt = hist[v];                              // elements with smaller d2
  // same-bin rows y' < y: dy'^2 <= v bounds the range; exact sqrt test (v <= 8192 << 2^24)
  const int r = __float2int_rd(sqrtf((float)v));
  int yp0 = 64 - r; if (yp0 < 0) yp0 = 0;
  int yp1 = 64 + r + 1; if (yp1 > y) yp1 = y;
  for (int yp = yp0; yp < yp1; ++yp){
    int dyp = yp - 64;
    int tt = v - dyp*dyp;                         // >= 0 by range construction
    int rr = __float2int_rn(sqrtf((float)tt));
    if (rr * rr == tt){
      cnt += (rr <= 64) ? 1 : 0;                  // x = 64 - rr
      cnt += (rr >= 1 && rr <= 63) ? 1 : 0;       // x = 64 + rr, distinct
    }
  }
  if (x > 64) cnt += 1;                           // mirror 128-x precedes
  sp[cnt] = j;
}

// ---------------- pass 1: per-chunk pipeline + from-zero scan ----------------
__global__ __launch_bounds__(128, 4)
void k_scan(const float* __restrict__ X,
            const float* __restrict__ dww, const float* __restrict__ dwb,
            const float* __restrict__ ipw,
            const float* __restrict__ c1w, const float* __restrict__ c1b,
            const float* __restrict__ xpw,
            const float* __restrict__ dtpw, const float* __restrict__ dtpb,
            const float* __restrict__ Alog,
            const int* __restrict__ sp,
            float* __restrict__ chA, float* __restrict__ chB,
            float* __restrict__ y0g, float4* __restrict__ ug4)
{
  const int c = blockIdx.x, b = blockIdx.y;
  const int c0 = c * TCH;
  const int tid = threadIdx.x;
  const float* Xb = X + (size_t)b * LTOT;

  __shared__ __align__(16) float s_pre[(TCH + 3) * 9];
  __shared__ __align__(16) float s_dt[8 * SD];
  __shared__ __align__(16) float s_dxm[8 * SD];     // dt * xm (s-independent product)
  __shared__ __align__(16) float s_Bv[16 * SD];
  __shared__ __align__(16) float s_Cv[16 * SD];

  // ---- step A: 12 gathers -> dwconv+silu -> u (cached to global) -> in_proj (xm half)
  if (tid < TCH + 3){
    const int m = tid;
    const int i = c0 - 3 + m;
    if (i < 0){
      #pragma unroll
      for (int d = 0; d < 8; ++d) s_pre[m*9 + d] = 0.f;
    } else {
      const int i2 = LTOT - 1 - i;
      const bool okm = (i > 0), okp = (i < LTOT - 1);
      int q[12];
      q[0]  = okm ? rho0(i - 1, sp) : 0;
      q[1]  =       rho0(i,     sp);
      q[2]  = okp ? rho0(i + 1, sp) : 0;
      q[3]  = okm ? rho1(i - 1, sp) : 0;
      q[4]  =       rho1(i,     sp);
      q[5]  = okp ? rho1(i + 1, sp) : 0;
      q[6]  = okm ? rho0(i2 + 1, sp) : 0;
      q[7]  =       rho0(i2,     sp);
      q[8]  = okp ? rho0(i2 - 1, sp) : 0;
      q[9]  = okm ? rho1(i2 + 1, sp) : 0;
      q[10] =       rho1(i2,     sp);
      q[11] = okp ? rho1(i2 - 1, sp) : 0;
      float xv[12];
      #pragma unroll
      for (int t = 0; t < 12; ++t) xv[t] = Xb[q[t]];
      if (!okm){ xv[0] = 0.f; xv[3] = 0.f; xv[6] = 0.f; xv[9]  = 0.f; }
      if (!okp){ xv[2] = 0.f; xv[5] = 0.f; xv[8] = 0.f; xv[11] = 0.f; }
      float u[4];
      #pragma unroll
      for (int k = 0; k < 4; ++k){
        float acc = dwb[k];
        acc = fmaf(dww[k*3+0], xv[k*3+0], acc);
        acc = fmaf(dww[k*3+1], xv[k*3+1], acc);
        acc = fmaf(dww[k*3+2], xv[k*3+2], acc);
        u[k] = siluf(acc);
      }
      ug4[(size_t)b * LTOT + i] = make_float4(u[0], u[1], u[2], u[3]);  // halo double-writes identical
      #pragma unroll
      for (int d = 0; d < 8; ++d){
        float acc =      ipw[d*4+0] * u[0];
        acc = fmaf(ipw[d*4+1], u[1], acc);
        acc = fmaf(ipw[d*4+2], u[2], acc);
        acc = fmaf(ipw[d*4+3], u[3], acc);
        s_pre[m*9 + d] = acc;
      }
    }
  }
  __syncthreads();

  // ---- step B: causal conv4+silu -> xm ; x_proj -> dt, B, C ; store dt and dt*xm
  if (tid < TCH){
    const int t = tid;
    float xm[8];
    #pragma unroll
    for (int d = 0; d < 8; ++d){
      float acc = c1b[d];
      #pragma unroll
      for (int tau = 0; tau < 4; ++tau)
        acc = fmaf(c1w[d*4+tau], s_pre[(t+tau)*9 + d], acc);
      xm[d] = siluf(acc);
    }
    float dtr = xpw[0] * xm[0];
    #pragma unroll
    for (int d = 1; d < 8; ++d) dtr = fmaf(xpw[d], xm[d], dtr);
    #pragma unroll
    for (int s = 0; s < 16; ++s){
      float acc = xpw[(1+s)*8] * xm[0];
      #pragma unroll
      for (int d = 1; d < 8; ++d) acc = fmaf(xpw[(1+s)*8+d], xm[d], acc);
      s_Bv[s*SD + t] = acc;
      float acc2 = xpw[(17+s)*8] * xm[0];
      #pragma unroll
      for (int d = 1; d < 8; ++d) acc2 = fmaf(xpw[(17+s)*8+d], xm[d], acc2);
      s_Cv[s*SD + t] = acc2;
    }
    #pragma unroll
    for (int d = 0; d < 8; ++d){
      float dtv = softplusf(fmaf(dtpw[d], dtr, dtpb[d]));
      s_dt[d*SD + t]  = dtv;
      s_dxm[d*SD + t] = dtv * xm[d];
    }
  }
  __syncthreads();

  // ---- step C: from-zero scan; emit y0 (s==0 lanes), chunk summary
  {
    const int d = tid >> 4, s = tid & 15;
    const float Ads = -__expf(Alog[tid]);   // tid == d*16+s (Alog small: fast exp fine)
    float h = 0.f, sdt = 0.f;
    const float* pdt = s_dt + d*SD;
    const float* pdx = s_dxm + d*SD;
    const float* pB  = s_Bv + s*SD;
    const float* pC  = s_Cv + s*SD;
    float* yb = y0g + ((size_t)b * NCH + c) * 768 + d * 96;
    for (int t0 = 0; t0 < TCH; t0 += 4){
      const float4 dt4 = *reinterpret_cast<const float4*>(pdt + t0);
      const float4 dx4 = *reinterpret_cast<const float4*>(pdx + t0);
      const float4 B4  = *reinterpret_cast<const float4*>(pB + t0);
      const float4 C4  = *reinterpret_cast<const float4*>(pC + t0);
      sdt += dt4.x + dt4.y + dt4.z + dt4.w;
      float y0, y1, y2, y3;
      { float dA = __expf(dt4.x*Ads); h = fmaf(dA, h, dx4.x*B4.x); y0 = h*C4.x; }
      { float dA = __expf(dt4.y*Ads); h = fmaf(dA, h, dx4.y*B4.y); y1 = h*C4.y; }
      { float dA = __expf(dt4.z*Ads); h = fmaf(dA, h, dx4.z*B4.z); y2 = h*C4.z; }
      { float dA = __expf(dt4.w*Ads); h = fmaf(dA, h, dx4.w*B4.w); y3 = h*C4.w; }
      y0 = red16(y0); y1 = red16(y1); y2 = red16(y2); y3 = red16(y3);
      if (s == 0)
        *reinterpret_cast<float4*>(yb + t0) = make_float4(y0, y1, y2, y3);
    }
    const size_t base = ((size_t)b * NCH + c) * 128 + tid;
    chA[base] = __expf(Ads * sdt);          // product of dA over the chunk
    chB[base] = h;
  }
}

// ---------------- combine level 1: per-group prefixes ----------------
__global__ __launch_bounds__(128) void k_comb1(const float* __restrict__ chA,
                                               const float* __restrict__ chB,
                                               float* __restrict__ hpre,
                                               float* __restrict__ apre,
                                               float* __restrict__ GA,
                                               float* __restrict__ GB){
  const int j = blockIdx.x;              // 0..63
  const int g = j >> 2, b = j & 3;
  const int idx = threadIdx.x;           // 0..127
  const size_t base = ((size_t)b * NCH + (size_t)g * GCH) * 128 + idx;
  float h = 0.f, a = 1.f;
  float A_[8], B_[8];
  #pragma unroll
  for (int m = 0; m < 8; ++m){ A_[m] = chA[base + (size_t)m*128]; B_[m] = chB[base + (size_t)m*128]; }
  for (int cc = 0; cc < GCH; cc += 8){
    float A2[8], B2[8];
    if (cc + 8 < GCH){
      #pragma unroll
      for (int m = 0; m < 8; ++m){ A2[m] = chA[base + (size_t)(cc+8+m)*128]; B2[m] = chB[base + (size_t)(cc+8+m)*128]; }
    } else {
      #pragma unroll
      for (int m = 0; m < 8; ++m){ A2[m] = 0.f; B2[m] = 0.f; }
    }
    #pragma unroll
    for (int m = 0; m < 8; ++m){
      hpre[base + (size_t)(cc+m)*128] = h;
      apre[base + (size_t)(cc+m)*128] = a;
      h = fmaf(A_[m], h, B_[m]);
      a *= A_[m];
    }
    #pragma unroll
    for (int m = 0; m < 8; ++m){ A_[m] = A2[m]; B_[m] = B2[m]; }
  }
  GA[(size_t)(g*4+b)*128 + idx] = a;
  GB[(size_t)(g*4+b)*128 + idx] = h;
}

// ---------------- pass 2: correction + epilogue (no serial chain, no gathers) ----------------
#define NBL (NB * LTOT)
__global__ __launch_bounds__(128, 4)
void k_corr(const float4* __restrict__ ug4,
            const float* __restrict__ ipw,
            const float* __restrict__ c1w, const float* __restrict__ c1b,
            const float* __restrict__ xpw,
            const float* __restrict__ dtpw, const float* __restrict__ dtpb,
            const float* __restrict__ Alog, const float* __restrict__ Dp,
            const float* __restrict__ opw,
            const float* __restrict__ lng, const float* __restrict__ lnb,
            const float* __restrict__ hpre, const float* __restrict__ apre,
            const float* __restrict__ GA, const float* __restrict__ GB,
            const float* __restrict__ y0g,
            float* __restrict__ outbuf)   // SoA: [e][b][i]
{
  const int c = blockIdx.x, b = blockIdx.y;
  const int c0 = c * TCH;
  const int tid = threadIdx.x;
  const size_t cb = (size_t)b * NCH + c;

  __shared__ __align__(16) float s_pre[(TCH + 3) * 9];  // 891 f; reused as s_yf (768 f, stride 96)
  __shared__ __align__(16) float s_sg[8 * 104];         // dt then in-place cumsum -> sigma
  __shared__ __align__(16) float s_xm[8 * 96];
  __shared__ __align__(16) float s_Ct[96 * 20];         // C transposed: [t][s], stride 20 (2-way banks, b128-aligned)
  __shared__ __align__(16) float s_zs[8 * 96];
  __shared__ __align__(16) float s_hA[256];             // [0:128) hin, [128:256) Ads
  float* s_yf = s_pre;

  // ---- stage 0: h_in assembly (folds comb2) + per-(d,s) constants to LDS
  {
    const int g = c >> 6;
    const float hp = hpre[cb * 128 + tid];
    const float ap = apre[cb * 128 + tid];
    float Hv = 0.f;
    for (int gp = 0; gp < g; ++gp){
      const float ga = GA[(size_t)gp*512 + (size_t)b*128 + tid];
      const float gb = GB[(size_t)gp*512 + (size_t)b*128 + tid];
      Hv = fmaf(ga, Hv, gb);
    }
    s_hA[tid]       = fmaf(ap, Hv, hp);     // hin[d*16+s]
    s_hA[128 + tid] = -__expf(Alog[tid]);   // Ads[d*16+s]
  }

  // ---- stage 1: u-cache load -> in_proj (pre + z gate)
  if (tid < TCH + 3){
    const int m = tid;
    const int i = c0 - 3 + m;
    if (i < 0){
      #pragma unroll
      for (int d = 0; d < 8; ++d) s_pre[m*9 + d] = 0.f;
    } else {
      const float4 u4 = ug4[(size_t)b * LTOT + i];
      const float u[4] = {u4.x, u4.y, u4.z, u4.w};
      #pragma unroll
      for (int d = 0; d < 8; ++d){
        float acc =      ipw[d*4+0] * u[0];
        acc = fmaf(ipw[d*4+1], u[1], acc);
        acc = fmaf(ipw[d*4+2], u[2], acc);
        acc = fmaf(ipw[d*4+3], u[3], acc);
        s_pre[m*9 + d] = acc;
      }
      if (m >= 3){
        const int t0 = m - 3;
        #pragma unroll
        for (int d = 0; d < 8; ++d){
          float acc =      ipw[(8+d)*4+0] * u[0];
          acc = fmaf(ipw[(8+d)*4+1], u[1], acc);
          acc = fmaf(ipw[(8+d)*4+2], u[2], acc);
          acc = fmaf(ipw[(8+d)*4+3], u[3], acc);
          s_zs[d*96 + t0] = siluf(acc);
        }
      }
    }
  }
  __syncthreads();

  // ---- stage 2: conv4+silu -> xm ; dt -> s_sg ; C -> s_Ct (t-major)
  if (tid < TCH){
    const int t = tid;
    float xm[8];
    #pragma unroll
    for (int d = 0; d < 8; ++d){
      float acc = c1b[d];
      #pragma unroll
      for (int tau = 0; tau < 4; ++tau)
        acc = fmaf(c1w[d*4+tau], s_pre[(t+tau)*9 + d], acc);
      float v = siluf(acc);
      xm[d] = v;
      s_xm[d*96 + t] = v;
    }
    float dtr = xpw[0] * xm[0];
    #pragma unroll
    for (int d = 1; d < 8; ++d) dtr = fmaf(xpw[d], xm[d], dtr);
    float* pct = s_Ct + t*20;
    #pragma unroll
    for (int s = 0; s < 16; ++s){
      float acc2 = xpw[(17+s)*8] * xm[0];
      #pragma unroll
      for (int d = 1; d < 8; ++d) acc2 = fmaf(xpw[(17+s)*8+d], xm[d], acc2);
      pct[s] = acc2;
    }
    #pragma unroll
    for (int d = 0; d < 8; ++d)
      s_sg[d*104 + t] = softplusf(fmaf(dtpw[d], dtr, dtpb[d]));
  }
  __syncthreads();

  // ---- stage 3: in-place inclusive cumsum of dt -> sigma (8 serial lanes)
  if (tid < 8){
    float* ps = s_sg + tid*104;
    float run = 0.f;
    for (int t0 = 0; t0 < TCH; t0 += 4){
      const float4 d4 = *reinterpret_cast<const float4*>(ps + t0);
      float r0 = run + d4.x, r1 = r0 + d4.y, r2 = r1 + d4.z, r3 = r2 + d4.w;
      *reinterpret_cast<float4*>(ps + t0) = make_float4(r0, r1, r2, r3);
      run = r3;
    }
  }
  __syncthreads();

  // ---- stage 4: correction, lanes = (d, tsub), in-register s-accumulation
  {
    const int d = tid >> 4, tsub = tid & 15;
    float w[16], A16[16];
    #pragma unroll
    for (int s = 0; s < 16; ++s){
      w[s]   = s_hA[d*16 + s];
      A16[s] = s_hA[128 + d*16 + s];
    }
    const float* py0 = y0g + cb * 768 + d * 96;
    for (int t = tsub; t < TCH; t += 16){
      const float sg = s_sg[d*104 + t];
      float acc = py0[t];
      const float* pc = s_Ct + t*20;
      #pragma unroll
      for (int s4 = 0; s4 < 16; s4 += 4){
        const float4 C4 = *reinterpret_cast<const float4*>(pc + s4);
        acc = fmaf(C4.x, __expf(A16[s4+0]*sg) * w[s4+0], acc);
        acc = fmaf(C4.y, __expf(A16[s4+1]*sg) * w[s4+1], acc);
        acc = fmaf(C4.z, __expf(A16[s4+2]*sg) * w[s4+2], acc);
        acc = fmaf(C4.w, __expf(A16[s4+3]*sg) * w[s4+3], acc);
      }
      s_yf[d*96 + t] = acc;
    }
  }
  __syncthreads();

  // ---- stage 5: epilogue: skip + gate + out_proj + LN -> SoA planes
  if (tid < TCH){
    const int t = tid;
    const int i = c0 + t;
    float y[8];
    #pragma unroll
    for (int d = 0; d < 8; ++d)
      y[d] = (s_yf[d*96 + t] + s_xm[d*96 + t] * Dp[d]) * s_zs[d*96 + t];
    float o[4];
    #pragma unroll
    for (int e = 0; e < 4; ++e){
      float acc = opw[e*8] * y[0];
      #pragma unroll
      for (int d = 1; d < 8; ++d) acc = fmaf(opw[e*8+d], y[d], acc);
      o[e] = acc;
    }
    const float mu = 0.25f * (o[0] + o[1] + o[2] + o[3]);
    const float v0 = o[0] - mu, v1 = o[1] - mu, v2 = o[2] - mu, v3 = o[3] - mu;
    const float inv = rsqrtf(0.25f * (v0*v0 + v1*v1 + v2*v2 + v3*v3) + 1e-5f);
    const size_t base = (size_t)b * LTOT + i;
    outbuf[0*NBL + base] = fmaf(v0 * inv, lng[0], lnb[0]);
    outbuf[1*NBL + base] = fmaf(v1 * inv, lng[1], lnb[1]);
    outbuf[2*NBL + base] = fmaf(v2 * inv, lng[2], lnb[2]);
    outbuf[3*NBL + base] = fmaf(v3 * inv, lng[3], lnb[3]);
  }
}

// ---------------- final gather + mean (SoA planes) ----------------
__global__ __launch_bounds__(256) void k_final(const float* __restrict__ outbuf,
                                               const int* __restrict__ sp,
                                               float* __restrict__ out){
  const int l = blockIdx.x * 256 + threadIdx.x;   // spatial flat index 0..L-1
  const int b = blockIdx.y;
  const int q0 = rho0(l, sp), q1 = rho1(l, sp);
  const int j  = LTOT - 1 - l;
  const int q2 = rho0(j, sp), q3 = rho1(j, sp);
  const size_t pb = (size_t)b * LTOT;
  out[pb + l] = 0.25f * (outbuf[0*NBL + pb + q0] + outbuf[1*NBL + pb + q1] +
                         outbuf[2*NBL + pb + q2] + outbuf[3*NBL + pb + q3]);
}

extern "C" void kernel_launch(void* const* d_in, const int* in_sizes, int n_in,
                              void* d_out, int out_size, void* d_ws, size_t ws_size,
                              hipStream_t stream) {
  const float* X    = (const float*)d_in[0];   // (4,6,128,128)
  const float* dww  = (const float*)d_in[1];   // (4,1,3)
  const float* dwb  = (const float*)d_in[2];   // (4)
  const float* ipw  = (const float*)d_in[3];   // (16,4)
  const float* c1w  = (const float*)d_in[4];   // (8,1,4)
  const float* c1b  = (const float*)d_in[5];   // (8)
  const float* xpw  = (const float*)d_in[6];   // (33,8)
  const float* dtpw = (const float*)d_in[7];   // (8,1)
  const float* dtpb = (const float*)d_in[8];   // (8)
  const float* Alog = (const float*)d_in[9];   // (8,16)
  const float* Dp   = (const float*)d_in[10];  // (8)
  const float* opw  = (const float*)d_in[11];  // (4,8)
  const float* lng  = (const float*)d_in[12];  // (4)
  const float* lnb  = (const float*)d_in[13];  // (4)
  float* out = (float*)d_out;

  // workspace layout (all rewritten every call):
  //   sp      16384 int                          (64 KB)
  //   chA/chB/hpre/apre  4 x 524288 f32          (8 MB)
  //   GA/GB              2 x 8192 f32
  //   ug      NB*LTOT float4                     (6.3 MB)
  //   y0g     NB*NCH*768 f32                     (12.6 MB)
  //   outbuf  4 planes x NB*LTOT f32 (SoA)       (6.3 MB)
  //   total ~ 33.4 MB
  int* wsI    = (int*)d_ws;
  int* sp     = wsI;
  float* chA  = (float*)(wsI + 16384);
  float* chB  = chA  + 524288;
  float* hpre = chB  + 524288;
  float* apre = hpre + 524288;
  float* GA   = apre + 524288;
  float* GB   = GA + 8192;
  float4* ug4 = (float4*)(GB + 8192);
  float* y0g  = (float*)(ug4) + (size_t)NB * LTOT * 4;
  float* outbuf = y0g + 3145728;

  k_rank<<<64, 256, 0, stream>>>(sp);
  k_scan<<<dim3(NCH, NB), 128, 0, stream>>>(X, dww, dwb, ipw, c1w, c1b, xpw,
      dtpw, dtpb, Alog, sp, chA, chB, y0g, ug4);
  k_comb1<<<64, 128, 0, stream>>>(chA, chB, hpre, apre, GA, GB);
  k_corr<<<dim3(NCH, NB), 128, 0, stream>>>(ug4, ipw, c1w, c1b, xpw,
      dtpw, dtpb, Alog, Dp, opw, lng, lnb, hpre, apre, GA, GB, y0g, outbuf);
  k_final<<<dim3(LTOT / 256, NB), 256, 0, stream>>>(outbuf, sp, out);
}